// Round 2
// baseline (12204.242 us; speedup 1.0000x reference)
//
#include <hip/hip_runtime.h>
#include <hip/hip_bf16.h>
#include <hip/hip_cooperative_groups.h>

namespace cg = cooperative_groups;

#define VV 32000
#define EE 256
#define HH 512
#define BB 64
#define TT 64
#define SS 64
#define G3 1536   // 3*H

typedef __attribute__((ext_vector_type(8))) short bf16x8;
typedef __attribute__((ext_vector_type(4))) float f32x4;

__device__ __forceinline__ void async16(void* lds, const void* g) {
  __builtin_amdgcn_global_load_lds((const __attribute__((address_space(1))) void*)g,
                                   (__attribute__((address_space(3))) void*)lds, 16, 0, 0);
}

__device__ __forceinline__ float sigmoid_fast(float x) {
  return 1.0f / (1.0f + __expf(-x));
}
__device__ __forceinline__ float tanh_fast(float x) {
  x = fminf(fmaxf(x, -15.f), 15.f);
  float e = __expf(2.f * x);
  return (e - 1.f) / (e + 1.f);
}

// ---------------- generic 2D transpose: dst[C][R] = src[R][C]^T (R,C multiples of 32)
__global__ __launch_bounds__(256) void transpose_kernel(float* __restrict__ dst,
                                                        const float* __restrict__ src,
                                                        int R, int C) {
  __shared__ float tile[32][33];
  int c0 = blockIdx.x * 32, r0 = blockIdx.y * 32;
  int x = threadIdx.x, y = threadIdx.y;     // block (32,8)
  for (int i = y; i < 32; i += 8) tile[i][x] = src[(size_t)(r0 + i) * C + c0 + x];
  __syncthreads();
  for (int i = y; i < 32; i += 8) dst[(size_t)(c0 + i) * R + r0 + x] = tile[x][i];
}

// ---------------- fp32 -> bf16 cast
__global__ __launch_bounds__(256) void cast_kernel(const float* __restrict__ src,
                                                   __hip_bfloat16* __restrict__ dst, int n) {
  for (int i = blockIdx.x * blockDim.x + threadIdx.x; i < n; i += gridDim.x * blockDim.x)
    dst[i] = __float2bfloat16(src[i]);
}

// ---------------- transpose initial hidden state into [h][b] layout
__global__ __launch_bounds__(256) void hsT_kernel(const float* __restrict__ hs,
                                                  float* __restrict__ h0T,
                                                  float* __restrict__ h1T) {
  int i = blockIdx.x * 256 + threadIdx.x;   // 0..32767
  int b = i >> 9, h = i & 511;
  h0T[h * BB + b] = hs[b * HH + h];
  h1T[h * BB + b] = hs[BB * HH + b * HH + h];
}

// ---------------- tiled fp32 GEMM: C[m][n] = sum_k A[row(m)][k]*Bk[k][n] (+bias[n])
// row(m) = Xtb ? Xtb[(m&63)*TT + (m>>6)] : m   (emb gather for gix)
// tile: M=64, N=128, K-chunks of 32. grid = (M/64, N/128)
__global__ __launch_bounds__(256) void gemm32_kernel(const float* __restrict__ A,
                                                     const int* __restrict__ Xtb,
                                                     const float* __restrict__ Bk,
                                                     const float* __restrict__ bias,
                                                     float* __restrict__ C,
                                                     int N, int K, int ldb) {
  __shared__ float Xs[32][65];    // [k][m]
  __shared__ float Ws[32][129];   // [k][n]
  __shared__ int toks[64];
  int m0 = blockIdx.x * 64, n0 = blockIdx.y * 128;
  int tid = threadIdx.x;
  if (tid < 64) {
    int m = m0 + tid;
    toks[tid] = Xtb ? Xtb[(m & 63) * TT + (m >> 6)] : m;
  }
  __syncthreads();
  float acc[4][8];
#pragma unroll
  for (int i = 0; i < 4; ++i)
#pragma unroll
    for (int j = 0; j < 8; ++j) acc[i][j] = 0.f;
  int mi = (tid >> 4) * 4;   // 4 m per thread
  int ni = (tid & 15) * 8;   // 8 n per thread
  for (int kc = 0; kc < K; kc += 32) {
#pragma unroll
    for (int i = 0; i < 16; ++i) {
      int idx = tid + i * 256;          // 0..4095
      int kk = idx >> 7, nn = idx & 127;
      Ws[kk][nn] = Bk[(size_t)(kc + kk) * ldb + n0 + nn];
    }
#pragma unroll
    for (int i = 0; i < 8; ++i) {
      int idx = tid + i * 256;          // 0..2047
      int mm = idx >> 5, kk = idx & 31;
      Xs[kk][mm] = A[(size_t)toks[mm] * K + kc + kk];
    }
    __syncthreads();
#pragma unroll
    for (int k = 0; k < 32; ++k) {
      float xv[4], wv[8];
#pragma unroll
      for (int i = 0; i < 4; ++i) xv[i] = Xs[k][mi + i];
#pragma unroll
      for (int j = 0; j < 8; ++j) wv[j] = Ws[k][ni + j];
#pragma unroll
      for (int i = 0; i < 4; ++i)
#pragma unroll
        for (int j = 0; j < 8; ++j) acc[i][j] += xv[i] * wv[j];
    }
    __syncthreads();
  }
#pragma unroll
  for (int i = 0; i < 4; ++i) {
    int m = m0 + mi + i;
#pragma unroll
    for (int j = 0; j < 8; ++j) {
      int n = n0 + ni + j;
      C[(size_t)m * N + n] = acc[i][j] + (bias ? bias[n] : 0.f);
    }
  }
}

// ---------------- persistent recurrent kernel (cooperative, 256 blocks x 256 threads)
struct RecArgs {
  const float* WqT; const float* keysp; const float* enc; const float* wv;
  const int* vlen;
  const float* WT0; const float* WTh0; const float* gix; const float* b_hh0;
  const float* WT1; const float* WTh1; const float* b_ih1; const float* b_hh1;
  float* ctxT; float* h0T0; float* h0T1; float* h1T0; float* h1T1;
  __hip_bfloat16* outsb;
};

__device__ __forceinline__ void gru_accum(const float* __restrict__ X,
                                          const float* __restrict__ W,
                                          int kbase, int j0, int lane,
                                          float& r0, float& r1, float& z0, float& z1,
                                          float& a0, float& a1) {
#pragma unroll 4
  for (int k = 0; k < 256; ++k) {
    int kk = kbase + k;
    float x = X[kk * BB + lane];
    const float* wr = W + kk * G3 + j0;
    float2 wv_r = *(const float2*)(wr);
    float2 wv_z = *(const float2*)(wr + 512);
    float2 wv_n = *(const float2*)(wr + 1024);
    r0 += wv_r.x * x; r1 += wv_r.y * x;
    z0 += wv_z.x * x; z1 += wv_z.y * x;
    a0 += wv_n.x * x; a1 += wv_n.y * x;
  }
}

template <int LAYER>
__device__ __forceinline__ void gru_layer(const float* __restrict__ Xt,   // input part, [512][64]
                                          const float* __restrict__ Ht,   // hidden, [512][64]
                                          const float* __restrict__ Wi,
                                          const float* __restrict__ Wh,
                                          const float* __restrict__ giOrBih,
                                          const float* __restrict__ bhh,
                                          float* __restrict__ Hnxt,
                                          __hip_bfloat16* __restrict__ outsb, int t,
                                          int blk, int w, int lane, int tid,
                                          float (*red)[4][64]) {
  const int j0 = 2 * blk;
  float r0 = 0, r1 = 0, z0 = 0, z1 = 0, a0 = 0, a1 = 0;
  if (w < 2) gru_accum(Xt, Wi, (w & 1) * 256, j0, lane, r0, r1, z0, z1, a0, a1);
  else       gru_accum(Ht, Wh, (w & 1) * 256, j0, lane, r0, r1, z0, z1, a0, a1);
  red[0][w][lane] = r0; red[1][w][lane] = r1;
  red[2][w][lane] = z0; red[3][w][lane] = z1;
  red[4][w][lane] = a0; red[5][w][lane] = a1;
  __syncthreads();
  if (tid < 128) {
    int b = tid & 63, jj = tid >> 6;
    int j = j0 + jj;
    float R  = red[jj][0][b] + red[jj][1][b] + red[jj][2][b] + red[jj][3][b];
    float Z  = red[2 + jj][0][b] + red[2 + jj][1][b] + red[2 + jj][2][b] + red[2 + jj][3][b];
    float IN = red[4 + jj][0][b] + red[4 + jj][1][b];
    float HN = red[4 + jj][2][b] + red[4 + jj][3][b];
    float gr, gz, gn;
    if (LAYER == 0) {
      const float* gx = giOrBih + b * G3;
      gr = gx[j]; gz = gx[j + 512]; gn = gx[j + 1024];
    } else {
      gr = giOrBih[j]; gz = giOrBih[j + 512]; gn = giOrBih[j + 1024];
    }
    float r = sigmoid_fast(gr + bhh[j] + R);
    float z = sigmoid_fast(gz + bhh[j + 512] + Z);
    float n = tanh_fast(gn + IN + r * (bhh[j + 1024] + HN));
    float hold = Ht[j * BB + b];
    float hv = (1.f - z) * n + z * hold;
    Hnxt[j * BB + b] = hv;
    if (LAYER == 1) outsb[(t * BB + b) * HH + j] = __float2bfloat16(hv);
  }
}

__global__ __launch_bounds__(256) void recurrent_kernel(RecArgs a) {
  cg::grid_group grid = cg::this_grid();
  const int blk = blockIdx.x, tid = threadIdx.x;
  const int w = __builtin_amdgcn_readfirstlane(tid >> 6);
  const int lane = tid & 63;

  __shared__ float sH[HH];
  __shared__ float sQ[HH];
  __shared__ float sAttn[SS];
  __shared__ float red[6][4][64];

  float* h0buf[2] = {a.h0T0, a.h0T1};
  float* h1buf[2] = {a.h1T0, a.h1T1};

  for (int t = 0; t < TT; ++t) {
    const float* h0cur = h0buf[t & 1];
    float* h0nxt = h0buf[(t + 1) & 1];
    const float* h1cur = h1buf[t & 1];
    float* h1nxt = h1buf[(t + 1) & 1];

    // ---- Phase A: attention, blocks 0..63 (b = blk) ----
    if (blk < BB) {
      const int b = blk;
      sH[tid] = h1cur[tid * BB + b];
      sH[tid + 256] = h1cur[(tid + 256) * BB + b];
      __syncthreads();
      float q0 = 0.f, q1 = 0.f;
#pragma unroll 8
      for (int h = 0; h < HH; ++h) {
        float x = sH[h];
        float2 wq = *(const float2*)&a.WqT[h * HH + 2 * tid];
        q0 += wq.x * x; q1 += wq.y * x;
      }
      sQ[2 * tid] = q0; sQ[2 * tid + 1] = q1;
      __syncthreads();
      int vl = a.vlen[b];
      for (int s = w; s < SS; s += 4) {
        const float* kp = a.keysp + (b * SS + s) * HH;
        float p = 0.f;
#pragma unroll
        for (int h = lane; h < HH; h += 64)
          p += tanh_fast(sQ[h] + kp[h]) * a.wv[h];
#pragma unroll
        for (int off = 32; off > 0; off >>= 1) p += __shfl_down(p, off);
        if (lane == 0) sAttn[s] = (s < vl) ? p : -1e6f;
      }
      __syncthreads();
      if (w == 0) {
        float v = sAttn[lane];
        float mx = v;
        for (int off = 32; off > 0; off >>= 1) mx = fmaxf(mx, __shfl_xor(mx, off));
        float e = __expf(v - mx);
        float sm = e;
        for (int off = 32; off > 0; off >>= 1) sm += __shfl_xor(sm, off);
        sAttn[lane] = e / sm;
      }
      __syncthreads();
      float c0 = 0.f, c1 = 0.f;
#pragma unroll 4
      for (int s = 0; s < SS; ++s) {
        float at = sAttn[s];
        float2 ev = *(const float2*)&a.enc[(b * SS + s) * HH + 2 * tid];
        c0 += at * ev.x; c1 += at * ev.y;
      }
      a.ctxT[(2 * tid) * BB + b] = c0;
      a.ctxT[(2 * tid + 1) * BB + b] = c1;
    }
    grid.sync();

    // ---- Phase B: GRU layer 0 ----
    gru_layer<0>(a.ctxT, h0cur, a.WT0, a.WTh0,
                 a.gix + (size_t)t * BB * G3, a.b_hh0, h0nxt,
                 nullptr, t, blk, w, lane, tid, red);
    grid.sync();

    // ---- Phase C: GRU layer 1 (+ emit bf16 outs) ----
    gru_layer<1>(h0nxt, h1cur, a.WT1, a.WTh1,
                 a.b_ih1, a.b_hh1, h1nxt,
                 a.outsb, t, blk, w, lane, tid, red);
    grid.sync();
  }
}

// ---------------- final dense: C[m,v] = A[m,:] . Bt[v,:] + bias[v], scatter to [B,T,V]
__global__ __launch_bounds__(256) void dense_kernel(const __hip_bfloat16* __restrict__ A,
                                                    const __hip_bfloat16* __restrict__ Bt,
                                                    const float* __restrict__ bias,
                                                    float* __restrict__ out) {
  __shared__ __align__(16) short As[128 * 64];
  __shared__ __align__(16) short Bs[128 * 64];
  int mt = blockIdx.x;         // 0..31
  int nt = blockIdx.y;         // 0..249
  int tid = threadIdx.x;
  int w = tid >> 6, lane = tid & 63;
  int wm = w >> 1, wn = w & 1;
  f32x4 acc[4][4];
#pragma unroll
  for (int m = 0; m < 4; ++m)
#pragma unroll
    for (int n = 0; n < 4; ++n) acc[m][n] = (f32x4)0.f;

  const short* Ag = (const short*)A + (size_t)(mt * 128) * 512;
  const short* Bg = (const short*)Bt + (size_t)(nt * 128) * 512;

  for (int kt = 0; kt < 8; ++kt) {
    int k0 = kt * 64;
#pragma unroll
    for (int c = 0; c < 4; ++c) {
      int chunk = w * 4 + c;                  // 0..15, wave-uniform
      int row = chunk * 8 + (lane >> 3);      // 0..127
      int col = (lane & 7) * 8;               // bf16 col within 64
      async16(As + chunk * 512, Ag + (size_t)row * 512 + k0 + col);
      async16(Bs + chunk * 512, Bg + (size_t)row * 512 + k0 + col);
    }
    __syncthreads();
#pragma unroll
    for (int kk = 0; kk < 2; ++kk) {
      int krow = kk * 32 + (lane >> 4) * 8;
      bf16x8 af[4], bf[4];
#pragma unroll
      for (int m = 0; m < 4; ++m) {
        int r = wm * 64 + m * 16 + (lane & 15);
        af[m] = *(const bf16x8*)&As[r * 64 + krow];
      }
#pragma unroll
      for (int n = 0; n < 4; ++n) {
        int r = wn * 64 + n * 16 + (lane & 15);
        bf[n] = *(const bf16x8*)&Bs[r * 64 + krow];
      }
#pragma unroll
      for (int m = 0; m < 4; ++m)
#pragma unroll
        for (int n = 0; n < 4; ++n)
          acc[m][n] = __builtin_amdgcn_mfma_f32_16x16x32_bf16(af[m], bf[n], acc[m][n], 0, 0, 0);
    }
    __syncthreads();
  }
#pragma unroll
  for (int m = 0; m < 4; ++m) {
    int rbase = mt * 128 + wm * 64 + m * 16 + (lane >> 4) * 4;
#pragma unroll
    for (int n = 0; n < 4; ++n) {
      int v = nt * 128 + wn * 64 + n * 16 + (lane & 15);
      float bv = bias[v];
#pragma unroll
      for (int r = 0; r < 4; ++r) {
        int mi = rbase + r;                  // mi = t*64 + b
        size_t off = (size_t)(mi & 63) * (TT * VV) + (size_t)(mi >> 6) * VV + v;
        out[off] = acc[m][n][r] + bv;
      }
    }
  }
}

extern "C" void kernel_launch(void* const* d_in, const int* in_sizes, int n_in,
                              void* d_out, int out_size, void* d_ws, size_t ws_size,
                              hipStream_t stream) {
  const int*   X     = (const int*)d_in[0];
  const float* enc   = (const float*)d_in[1];
  const float* hs    = (const float*)d_in[2];
  const int*   vlen  = (const int*)d_in[3];
  const float* emb   = (const float*)d_in[4];
  const float* Wq    = (const float*)d_in[5];
  const float* Wk    = (const float*)d_in[6];
  const float* wv    = (const float*)d_in[7];
  const float* W_ih0 = (const float*)d_in[8];
  const float* W_hh0 = (const float*)d_in[9];
  const float* b_ih0 = (const float*)d_in[10];
  const float* b_hh0 = (const float*)d_in[11];
  const float* W_ih1 = (const float*)d_in[12];
  const float* W_hh1 = (const float*)d_in[13];
  const float* b_ih1 = (const float*)d_in[14];
  const float* b_hh1 = (const float*)d_in[15];
  const float* dW    = (const float*)d_in[16];
  const float* db    = (const float*)d_in[17];
  float* out = (float*)d_out;

  char* wp = (char*)d_ws;
  auto alloc = [&](size_t bytes) { char* p = wp; wp += (bytes + 255) & ~(size_t)255; return p; };
  __hip_bfloat16* dWb   = (__hip_bfloat16*)alloc((size_t)VV * HH * 2);
  __hip_bfloat16* outsb = (__hip_bfloat16*)alloc((size_t)TT * BB * HH * 2);
  float* keysp = (float*)alloc((size_t)BB * SS * HH * 4);
  float* gix   = (float*)alloc((size_t)TT * BB * G3 * 4);
  float* WqT   = (float*)alloc((size_t)HH * HH * 4);
  float* WkT   = (float*)alloc((size_t)HH * HH * 4);
  float* WT0   = (float*)alloc((size_t)(HH + EE) * G3 * 4);
  float* WTh0  = (float*)alloc((size_t)HH * G3 * 4);
  float* WT1   = (float*)alloc((size_t)HH * G3 * 4);
  float* WTh1  = (float*)alloc((size_t)HH * G3 * 4);
  float* ctxT  = (float*)alloc((size_t)HH * BB * 4);
  float* h0T0  = (float*)alloc((size_t)HH * BB * 4);
  float* h0T1  = (float*)alloc((size_t)HH * BB * 4);
  float* h1T0  = (float*)alloc((size_t)HH * BB * 4);
  float* h1T1  = (float*)alloc((size_t)HH * BB * 4);

  dim3 tb(32, 8);
  transpose_kernel<<<dim3(HH / 32, HH / 32), tb, 0, stream>>>(WqT, Wq, HH, HH);
  transpose_kernel<<<dim3(HH / 32, HH / 32), tb, 0, stream>>>(WkT, Wk, HH, HH);
  transpose_kernel<<<dim3((HH + EE) / 32, G3 / 32), tb, 0, stream>>>(WT0, W_ih0, G3, HH + EE);
  transpose_kernel<<<dim3(HH / 32, G3 / 32), tb, 0, stream>>>(WTh0, W_hh0, G3, HH);
  transpose_kernel<<<dim3(HH / 32, G3 / 32), tb, 0, stream>>>(WT1, W_ih1, G3, HH);
  transpose_kernel<<<dim3(HH / 32, G3 / 32), tb, 0, stream>>>(WTh1, W_hh1, G3, HH);
  cast_kernel<<<2048, 256, 0, stream>>>(dW, dWb, VV * HH);
  hsT_kernel<<<128, 256, 0, stream>>>(hs, h0T0, h1T0);

  // keysp[b*S+s][n] = enc row . WkT   (M=4096,N=512,K=512)
  gemm32_kernel<<<dim3(BB * SS / 64, HH / 128), 256, 0, stream>>>(
      enc, nullptr, WkT, nullptr, keysp, HH, HH, HH);
  // gix[t*B+b][n] = emb[X[b,t]] . WT0_embpart + b_ih0   (M=4096,N=1536,K=256)
  gemm32_kernel<<<dim3(TT * BB / 64, G3 / 128), 256, 0, stream>>>(
      emb, X, WT0 + (size_t)HH * G3, b_ih0, gix, G3, EE, G3);

  RecArgs args;
  args.WqT = WqT; args.keysp = keysp; args.enc = enc; args.wv = wv; args.vlen = vlen;
  args.WT0 = WT0; args.WTh0 = WTh0; args.gix = gix; args.b_hh0 = b_hh0;
  args.WT1 = WT1; args.WTh1 = WTh1; args.b_ih1 = b_ih1; args.b_hh1 = b_hh1;
  args.ctxT = ctxT; args.h0T0 = h0T0; args.h0T1 = h0T1; args.h1T0 = h1T0; args.h1T1 = h1T1;
  args.outsb = outsb;
  void* kp[] = {&args};
  hipLaunchCooperativeKernel(reinterpret_cast<void*>(recurrent_kernel),
                             dim3(256), dim3(256), kp, 0, stream);

  dense_kernel<<<dim3(32, 250), 256, 0, stream>>>(outsb, dWb, db, out);
}

// Round 3
// 10265.176 us; speedup vs baseline: 1.1889x; 1.1889x over previous
//
#include <hip/hip_runtime.h>
#include <hip/hip_bf16.h>
#include <hip/hip_cooperative_groups.h>

namespace cg = cooperative_groups;

#define VV 32000
#define EE 256
#define HH 512
#define BB 64
#define TT 64
#define SS 64
#define G3 1536   // 3*H

typedef __attribute__((ext_vector_type(8))) short bf16x8;
typedef __attribute__((ext_vector_type(4))) float f32x4;

__device__ __forceinline__ void async16(void* lds, const void* g) {
  __builtin_amdgcn_global_load_lds((const __attribute__((address_space(1))) void*)g,
                                   (__attribute__((address_space(3))) void*)lds, 16, 0, 0);
}

__device__ __forceinline__ float sigmoid_fast(float x) {
  return 1.0f / (1.0f + __expf(-x));
}
__device__ __forceinline__ float tanh_fast(float x) {
  x = fminf(fmaxf(x, -15.f), 15.f);
  float e = __expf(2.f * x);
  return (e - 1.f) / (e + 1.f);
}

// ---------------- strided 2D transpose: dst[c][r] = src[r*ld + off + c]
__global__ __launch_bounds__(256) void transpose_kernel(float* __restrict__ dst,
                                                        const float* __restrict__ src,
                                                        int R, int C, int ld, int off) {
  __shared__ float tile[32][33];
  int c0 = blockIdx.x * 32, r0 = blockIdx.y * 32;
  int x = threadIdx.x, y = threadIdx.y;     // block (32,8)
  for (int i = y; i < 32; i += 8) tile[i][x] = src[(size_t)(r0 + i) * ld + off + c0 + x];
  __syncthreads();
  for (int i = y; i < 32; i += 8) dst[(size_t)(c0 + i) * R + r0 + x] = tile[x][i];
}

// ---------------- fp32 -> bf16 cast
__global__ __launch_bounds__(256) void cast_kernel(const float* __restrict__ src,
                                                   __hip_bfloat16* __restrict__ dst, int n) {
  for (int i = blockIdx.x * blockDim.x + threadIdx.x; i < n; i += gridDim.x * blockDim.x)
    dst[i] = __float2bfloat16(src[i]);
}

// ---------------- transpose initial hidden state into [h][b] layout
__global__ __launch_bounds__(256) void hsT_kernel(const float* __restrict__ hs,
                                                  float* __restrict__ h0T,
                                                  float* __restrict__ h1T) {
  int i = blockIdx.x * 256 + threadIdx.x;   // 0..32767
  int b = i >> 9, h = i & 511;
  h0T[h * BB + b] = hs[b * HH + h];
  h1T[h * BB + b] = hs[BB * HH + b * HH + h];
}

// ---------------- tiled fp32 GEMM: C[m][n] = sum_k A[row(m)][k]*Bk[k][n] (+bias[n])
__global__ __launch_bounds__(256) void gemm32_kernel(const float* __restrict__ A,
                                                     const int* __restrict__ Xtb,
                                                     const float* __restrict__ Bk,
                                                     const float* __restrict__ bias,
                                                     float* __restrict__ C,
                                                     int N, int K, int ldb) {
  __shared__ float Xs[32][65];    // [k][m]
  __shared__ float Ws[32][129];   // [k][n]
  __shared__ int toks[64];
  int m0 = blockIdx.x * 64, n0 = blockIdx.y * 128;
  int tid = threadIdx.x;
  if (tid < 64) {
    int m = m0 + tid;
    toks[tid] = Xtb ? Xtb[(m & 63) * TT + (m >> 6)] : m;
  }
  __syncthreads();
  float acc[4][8];
#pragma unroll
  for (int i = 0; i < 4; ++i)
#pragma unroll
    for (int j = 0; j < 8; ++j) acc[i][j] = 0.f;
  int mi = (tid >> 4) * 4;   // 4 m per thread
  int ni = (tid & 15) * 8;   // 8 n per thread
  for (int kc = 0; kc < K; kc += 32) {
#pragma unroll
    for (int i = 0; i < 16; ++i) {
      int idx = tid + i * 256;          // 0..4095
      int kk = idx >> 7, nn = idx & 127;
      Ws[kk][nn] = Bk[(size_t)(kc + kk) * ldb + n0 + nn];
    }
#pragma unroll
    for (int i = 0; i < 8; ++i) {
      int idx = tid + i * 256;          // 0..2047
      int mm = idx >> 5, kk = idx & 31;
      Xs[kk][mm] = A[(size_t)toks[mm] * K + kc + kk];
    }
    __syncthreads();
#pragma unroll
    for (int k = 0; k < 32; ++k) {
      float xv[4], wv[8];
#pragma unroll
      for (int i = 0; i < 4; ++i) xv[i] = Xs[k][mi + i];
#pragma unroll
      for (int j = 0; j < 8; ++j) wv[j] = Ws[k][ni + j];
#pragma unroll
      for (int i = 0; i < 4; ++i)
#pragma unroll
        for (int j = 0; j < 8; ++j) acc[i][j] += xv[i] * wv[j];
    }
    __syncthreads();
  }
#pragma unroll
  for (int i = 0; i < 4; ++i) {
    int m = m0 + mi + i;
#pragma unroll
    for (int j = 0; j < 8; ++j) {
      int n = n0 + ni + j;
      C[(size_t)m * N + n] = acc[i][j] + (bias ? bias[n] : 0.f);
    }
  }
}

// ---------------- persistent recurrent kernel (cooperative, 256 blocks x 256 threads)
// Block blk owns output columns j0=2*blk, j0+1 of q, h0, h1. All weight slices
// for those columns live in LDS for the whole kernel -> zero steady-state
// global weight traffic. 4 grid.syncs per step.
struct RecArgs {
  const float *Wq, *W_ih0, *W_hh0, *W_ih1, *W_hh1;
  const float *b_hh0, *b_ih1, *b_hh1;
  const float *gix, *keysp, *enc, *wv;
  const int* vlen;
  float *qT, *ctxT, *h0T0, *h0T1, *h1T0, *h1T1;
  __hip_bfloat16* outsb;
};

__global__ __launch_bounds__(256) void recurrent_kernel(RecArgs a) {
  cg::grid_group grid = cg::this_grid();
  const int blk = blockIdx.x, tid = threadIdx.x;
  const int w = tid >> 6, lane = tid & 63;
  const int j0 = 2 * blk;

  __shared__ __align__(16) float WL0[1024][8];  // [k][slot], slots: r0,r1,z0,z1,n0,n1
  __shared__ __align__(16) float WL1[1024][8];
  __shared__ float QL[512][2];
  __shared__ float red[6][4][64];
  __shared__ float sQ[512];
  __shared__ float sWV[512];
  __shared__ float sAttn[64];

  // ---- one-time weight preload into LDS (rows of original matrices are contiguous) ----
  for (int idx = tid; idx < 1024; idx += 256) {
    int jj = idx >> 9, h = idx & 511;
    QL[h][jj] = a.Wq[(size_t)(j0 + jj) * HH + h];
  }
#pragma unroll
  for (int s = 0; s < 6; ++s) {
    int g = s >> 1, jj = s & 1;
    int r = g * 512 + j0 + jj;
    for (int h = tid; h < 512; h += 256) {
      WL0[h][s]       = a.W_ih0[(size_t)r * 768 + h];       // ctx part (cols 0..511 of E+H=768)
      WL0[512 + h][s] = a.W_hh0[(size_t)r * 512 + h];
      WL1[h][s]       = a.W_ih1[(size_t)r * 512 + h];
      WL1[512 + h][s] = a.W_hh1[(size_t)r * 512 + h];
    }
  }
  if (blk < BB)
    for (int idx = tid; idx < 512; idx += 256) sWV[idx] = a.wv[idx];
  __syncthreads();

  float* h0buf[2] = {a.h0T0, a.h0T1};
  float* h1buf[2] = {a.h1T0, a.h1T1};

  for (int t = 0; t < TT; ++t) {
    const float* h0cur = h0buf[t & 1];
    float* h0nxt = h0buf[(t + 1) & 1];
    const float* h1cur = h1buf[t & 1];
    float* h1nxt = h1buf[(t + 1) & 1];

    // ---- P0: q projection, j-distributed: q[j0..j0+1][all b] ----
    {
      float q0 = 0.f, q1 = 0.f;
      const float* xp = h1cur + w * 128 * BB;
#pragma unroll 8
      for (int k = 0; k < 128; ++k) {
        float x = xp[k * BB + lane];
        float2 wq = *(const float2*)&QL[w * 128 + k][0];
        q0 += wq.x * x; q1 += wq.y * x;
      }
      red[0][w][lane] = q0; red[1][w][lane] = q1;
      __syncthreads();
      if (tid < 128) {
        int b = tid & 63, jj = tid >> 6;
        float q = red[jj][0][b] + red[jj][1][b] + red[jj][2][b] + red[jj][3][b];
        a.qT[(j0 + jj) * BB + b] = q;
      }
    }
    grid.sync();

    // ---- P1: scores + softmax + context (blocks 0..63, b = blk) ----
    if (blk < BB) {
      const int b = blk;
      for (int idx = tid; idx < 512; idx += 256) sQ[idx] = a.qT[idx * BB + b];
      __syncthreads();
      int vl = a.vlen[b];
      for (int s = w; s < SS; s += 4) {
        const float* kp = a.keysp + (size_t)(b * SS + s) * HH;
        float p = 0.f;
#pragma unroll
        for (int h = lane; h < HH; h += 64)
          p += tanh_fast(sQ[h] + kp[h]) * sWV[h];
#pragma unroll
        for (int off = 32; off > 0; off >>= 1) p += __shfl_down(p, off);
        if (lane == 0) sAttn[s] = (s < vl) ? p : -1e6f;
      }
      __syncthreads();
      if (w == 0) {
        float v = sAttn[lane];
        float mx = v;
        for (int off = 32; off > 0; off >>= 1) mx = fmaxf(mx, __shfl_xor(mx, off));
        float e = __expf(v - mx);
        float sm = e;
        for (int off = 32; off > 0; off >>= 1) sm += __shfl_xor(sm, off);
        sAttn[lane] = e / sm;
      }
      __syncthreads();
      float c0 = 0.f, c1 = 0.f;
#pragma unroll 4
      for (int s = 0; s < SS; ++s) {
        float at = sAttn[s];
        float2 ev = *(const float2*)&a.enc[(size_t)(b * SS + s) * HH + 2 * tid];
        c0 += at * ev.x; c1 += at * ev.y;
      }
      a.ctxT[(2 * tid) * BB + b] = c0;
      a.ctxT[(2 * tid + 1) * BB + b] = c1;
    }
    grid.sync();

    // ---- P2: GRU layer 0 -> h0nxt ----
    {
      float r0 = 0, r1 = 0, z0 = 0, z1 = 0, n0 = 0, n1 = 0;
      const float* xp = (w < 2) ? (a.ctxT + w * 256 * BB) : (h0cur + (w - 2) * 256 * BB);
      int kb = w * 256;
#pragma unroll 8
      for (int k = 0; k < 256; ++k) {
        float x = xp[k * BB + lane];
        float4 w4 = *(const float4*)&WL0[kb + k][0];
        float2 w2 = *(const float2*)&WL0[kb + k][4];
        r0 += w4.x * x; r1 += w4.y * x;
        z0 += w4.z * x; z1 += w4.w * x;
        n0 += w2.x * x; n1 += w2.y * x;
      }
      red[0][w][lane] = r0; red[1][w][lane] = r1;
      red[2][w][lane] = z0; red[3][w][lane] = z1;
      red[4][w][lane] = n0; red[5][w][lane] = n1;
      __syncthreads();
      if (tid < 128) {
        int b = tid & 63, jj = tid >> 6, j = j0 + jj;
        float R  = red[jj][0][b] + red[jj][1][b] + red[jj][2][b] + red[jj][3][b];
        float Z  = red[2 + jj][0][b] + red[2 + jj][1][b] + red[2 + jj][2][b] + red[2 + jj][3][b];
        float Nx = red[4 + jj][0][b] + red[4 + jj][1][b];
        float Nh = red[4 + jj][2][b] + red[4 + jj][3][b];
        const float* gx = a.gix + ((size_t)t * BB + b) * G3;
        float r = sigmoid_fast(gx[j] + a.b_hh0[j] + R);
        float z = sigmoid_fast(gx[j + 512] + a.b_hh0[j + 512] + Z);
        float n = tanh_fast(gx[j + 1024] + Nx + r * (a.b_hh0[j + 1024] + Nh));
        float hold = h0cur[j * BB + b];
        h0nxt[j * BB + b] = (1.f - z) * n + z * hold;
      }
    }
    grid.sync();

    // ---- P3: GRU layer 1 -> h1nxt (+ bf16 outs) ----
    {
      float r0 = 0, r1 = 0, z0 = 0, z1 = 0, n0 = 0, n1 = 0;
      const float* xp = (w < 2) ? (h0nxt + w * 256 * BB) : (h1cur + (w - 2) * 256 * BB);
      int kb = w * 256;
#pragma unroll 8
      for (int k = 0; k < 256; ++k) {
        float x = xp[k * BB + lane];
        float4 w4 = *(const float4*)&WL1[kb + k][0];
        float2 w2 = *(const float2*)&WL1[kb + k][4];
        r0 += w4.x * x; r1 += w4.y * x;
        z0 += w4.z * x; z1 += w4.w * x;
        n0 += w2.x * x; n1 += w2.y * x;
      }
      red[0][w][lane] = r0; red[1][w][lane] = r1;
      red[2][w][lane] = z0; red[3][w][lane] = z1;
      red[4][w][lane] = n0; red[5][w][lane] = n1;
      __syncthreads();
      if (tid < 128) {
        int b = tid & 63, jj = tid >> 6, j = j0 + jj;
        float R  = red[jj][0][b] + red[jj][1][b] + red[jj][2][b] + red[jj][3][b];
        float Z  = red[2 + jj][0][b] + red[2 + jj][1][b] + red[2 + jj][2][b] + red[2 + jj][3][b];
        float Nx = red[4 + jj][0][b] + red[4 + jj][1][b];
        float Nh = red[4 + jj][2][b] + red[4 + jj][3][b];
        float r = sigmoid_fast(a.b_ih1[j] + a.b_hh1[j] + R);
        float z = sigmoid_fast(a.b_ih1[j + 512] + a.b_hh1[j + 512] + Z);
        float n = tanh_fast(a.b_ih1[j + 1024] + Nx + r * (a.b_hh1[j + 1024] + Nh));
        float hv = (1.f - z) * n + z * h1cur[j * BB + b];
        h1nxt[j * BB + b] = hv;
        a.outsb[((size_t)t * BB + b) * HH + j] = __float2bfloat16(hv);
      }
    }
    grid.sync();
  }
}

// ---------------- final dense: C[m,v] = A[m,:] . Bt[v,:] + bias[v], scatter to [B,T,V]
__global__ __launch_bounds__(256) void dense_kernel(const __hip_bfloat16* __restrict__ A,
                                                    const __hip_bfloat16* __restrict__ Bt,
                                                    const float* __restrict__ bias,
                                                    float* __restrict__ out) {
  __shared__ __align__(16) short As[128 * 64];
  __shared__ __align__(16) short Bs[128 * 64];
  int mt = blockIdx.x;         // 0..31
  int nt = blockIdx.y;         // 0..249
  int tid = threadIdx.x;
  int w = tid >> 6, lane = tid & 63;
  int wm = w >> 1, wn = w & 1;
  f32x4 acc[4][4];
#pragma unroll
  for (int m = 0; m < 4; ++m)
#pragma unroll
    for (int n = 0; n < 4; ++n) acc[m][n] = (f32x4)0.f;

  const short* Ag = (const short*)A + (size_t)(mt * 128) * 512;
  const short* Bg = (const short*)Bt + (size_t)(nt * 128) * 512;

  for (int kt = 0; kt < 8; ++kt) {
    int k0 = kt * 64;
#pragma unroll
    for (int c = 0; c < 4; ++c) {
      int chunk = w * 4 + c;                  // 0..15, wave-uniform
      int row = chunk * 8 + (lane >> 3);      // 0..127
      int col = (lane & 7) * 8;               // bf16 col within 64
      async16(As + chunk * 512, Ag + (size_t)row * 512 + k0 + col);
      async16(Bs + chunk * 512, Bg + (size_t)row * 512 + k0 + col);
    }
    __syncthreads();
#pragma unroll
    for (int kk = 0; kk < 2; ++kk) {
      int krow = kk * 32 + (lane >> 4) * 8;
      bf16x8 af[4], bf[4];
#pragma unroll
      for (int m = 0; m < 4; ++m) {
        int r = wm * 64 + m * 16 + (lane & 15);
        af[m] = *(const bf16x8*)&As[r * 64 + krow];
      }
#pragma unroll
      for (int n = 0; n < 4; ++n) {
        int r = wn * 64 + n * 16 + (lane & 15);
        bf[n] = *(const bf16x8*)&Bs[r * 64 + krow];
      }
#pragma unroll
      for (int m = 0; m < 4; ++m)
#pragma unroll
        for (int n = 0; n < 4; ++n)
          acc[m][n] = __builtin_amdgcn_mfma_f32_16x16x32_bf16(af[m], bf[n], acc[m][n], 0, 0, 0);
    }
    __syncthreads();
  }
#pragma unroll
  for (int m = 0; m < 4; ++m) {
    int rbase = mt * 128 + wm * 64 + m * 16 + (lane >> 4) * 4;
#pragma unroll
    for (int n = 0; n < 4; ++n) {
      int v = nt * 128 + wn * 64 + n * 16 + (lane & 15);
      float bv = bias[v];
#pragma unroll
      for (int r = 0; r < 4; ++r) {
        int mi = rbase + r;                  // mi = t*64 + b
        size_t off = (size_t)(mi & 63) * (TT * VV) + (size_t)(mi >> 6) * VV + v;
        out[off] = acc[m][n][r] + bv;
      }
    }
  }
}

extern "C" void kernel_launch(void* const* d_in, const int* in_sizes, int n_in,
                              void* d_out, int out_size, void* d_ws, size_t ws_size,
                              hipStream_t stream) {
  const int*   X     = (const int*)d_in[0];
  const float* enc   = (const float*)d_in[1];
  const float* hs    = (const float*)d_in[2];
  const int*   vlen  = (const int*)d_in[3];
  const float* emb   = (const float*)d_in[4];
  const float* Wq    = (const float*)d_in[5];
  const float* Wk    = (const float*)d_in[6];
  const float* wv    = (const float*)d_in[7];
  const float* W_ih0 = (const float*)d_in[8];
  const float* W_hh0 = (const float*)d_in[9];
  const float* b_ih0 = (const float*)d_in[10];
  const float* b_hh0 = (const float*)d_in[11];
  const float* W_ih1 = (const float*)d_in[12];
  const float* W_hh1 = (const float*)d_in[13];
  const float* b_ih1 = (const float*)d_in[14];
  const float* b_hh1 = (const float*)d_in[15];
  const float* dW    = (const float*)d_in[16];
  const float* db    = (const float*)d_in[17];
  float* out = (float*)d_out;

  char* wp = (char*)d_ws;
  auto alloc = [&](size_t bytes) { char* p = wp; wp += (bytes + 255) & ~(size_t)255; return p; };
  __hip_bfloat16* dWb   = (__hip_bfloat16*)alloc((size_t)VV * HH * 2);
  __hip_bfloat16* outsb = (__hip_bfloat16*)alloc((size_t)TT * BB * HH * 2);
  float* keysp = (float*)alloc((size_t)BB * SS * HH * 4);
  float* gix   = (float*)alloc((size_t)TT * BB * G3 * 4);
  float* WkT   = (float*)alloc((size_t)HH * HH * 4);
  float* WT0e  = (float*)alloc((size_t)EE * G3 * 4);
  float* qT    = (float*)alloc((size_t)HH * BB * 4);
  float* ctxT  = (float*)alloc((size_t)HH * BB * 4);
  float* h0T0  = (float*)alloc((size_t)HH * BB * 4);
  float* h0T1  = (float*)alloc((size_t)HH * BB * 4);
  float* h1T0  = (float*)alloc((size_t)HH * BB * 4);
  float* h1T1  = (float*)alloc((size_t)HH * BB * 4);

  dim3 tb(32, 8);
  // WkT[h][n] = Wk[n][h]
  transpose_kernel<<<dim3(HH / 32, HH / 32), tb, 0, stream>>>(WkT, Wk, HH, HH, HH, 0);
  // WT0e[e][n] = W_ih0[n][512+e]  (emb part of W_ih0, ld=768)
  transpose_kernel<<<dim3(EE / 32, G3 / 32), tb, 0, stream>>>(WT0e, W_ih0, G3, EE, HH + EE, HH);
  cast_kernel<<<2048, 256, 0, stream>>>(dW, dWb, VV * HH);
  hsT_kernel<<<128, 256, 0, stream>>>(hs, h0T0, h1T0);

  // keysp[b*S+s][n] = enc row . WkT   (M=4096,N=512,K=512)
  gemm32_kernel<<<dim3(BB * SS / 64, HH / 128), 256, 0, stream>>>(
      enc, nullptr, WkT, nullptr, keysp, HH, HH, HH);
  // gix[t*B+b][n] = emb[X[b,t]] . WT0e + b_ih0   (M=4096,N=1536,K=256)
  gemm32_kernel<<<dim3(TT * BB / 64, G3 / 128), 256, 0, stream>>>(
      emb, X, WT0e, b_ih0, gix, G3, EE, G3);

  RecArgs args;
  args.Wq = Wq; args.W_ih0 = W_ih0; args.W_hh0 = W_hh0; args.W_ih1 = W_ih1; args.W_hh1 = W_hh1;
  args.b_hh0 = b_hh0; args.b_ih1 = b_ih1; args.b_hh1 = b_hh1;
  args.gix = gix; args.keysp = keysp; args.enc = enc; args.wv = wv; args.vlen = vlen;
  args.qT = qT; args.ctxT = ctxT;
  args.h0T0 = h0T0; args.h0T1 = h0T1; args.h1T0 = h1T0; args.h1T1 = h1T1;
  args.outsb = outsb;
  void* kp[] = {&args};
  hipLaunchCooperativeKernel(reinterpret_cast<void*>(recurrent_kernel),
                             dim3(256), dim3(256), kp, 0, stream);

  dense_kernel<<<dim3(32, 250), 256, 0, stream>>>(outsb, dWb, db, out);
}

// Round 4
// 7672.778 us; speedup vs baseline: 1.5906x; 1.3379x over previous
//
#include <hip/hip_runtime.h>
#include <hip/hip_bf16.h>
#include <hip/hip_cooperative_groups.h>

#define VV 32000
#define EE 256
#define HH 512
#define BB 64
#define TT 64
#define SS 64
#define G3 1536   // 3*H
#define NBLK 256

typedef __attribute__((ext_vector_type(8))) short bf16x8;
typedef __attribute__((ext_vector_type(4))) float f32x4;

__device__ __forceinline__ void async16(void* lds, const void* g) {
  __builtin_amdgcn_global_load_lds((const __attribute__((address_space(1))) void*)g,
                                   (__attribute__((address_space(3))) void*)lds, 16, 0, 0);
}

__device__ __forceinline__ float sigmoid_fast(float x) {
  return 1.0f / (1.0f + __expf(-x));
}
__device__ __forceinline__ float tanh_fast(float x) {
  x = fminf(fmaxf(x, -15.f), 15.f);
  float e = __expf(2.f * x);
  return (e - 1.f) / (e + 1.f);
}

// hand-rolled one-shot grid barrier: slot idx used exactly once per launch
__device__ __forceinline__ void gbar(int* bar, int idx) {
  __syncthreads();   // drains vmcnt per wave -> all block stores in L2
  if (threadIdx.x == 0) {
    __builtin_amdgcn_fence(__ATOMIC_RELEASE, "agent");   // wbl2: L2 -> coherence point
    __hip_atomic_fetch_add(&bar[idx], 1, __ATOMIC_RELAXED, __HIP_MEMORY_SCOPE_AGENT);
    while (__hip_atomic_load(&bar[idx], __ATOMIC_RELAXED, __HIP_MEMORY_SCOPE_AGENT) < NBLK) {}
    __builtin_amdgcn_fence(__ATOMIC_ACQUIRE, "agent");   // inv L1/L2
  }
  __syncthreads();
}

// ---------------- strided 2D transpose: dst[c][r] = src[r*ld + off + c]
__global__ __launch_bounds__(256) void transpose_kernel(float* __restrict__ dst,
                                                        const float* __restrict__ src,
                                                        int R, int C, int ld, int off) {
  __shared__ float tile[32][33];
  int c0 = blockIdx.x * 32, r0 = blockIdx.y * 32;
  int x = threadIdx.x, y = threadIdx.y;     // block (32,8)
  for (int i = y; i < 32; i += 8) tile[i][x] = src[(size_t)(r0 + i) * ld + off + c0 + x];
  __syncthreads();
  for (int i = y; i < 32; i += 8) dst[(size_t)(c0 + i) * R + r0 + x] = tile[x][i];
}

// ---------------- fp32 -> bf16 cast
__global__ __launch_bounds__(256) void cast_kernel(const float* __restrict__ src,
                                                   __hip_bfloat16* __restrict__ dst, int n) {
  for (int i = blockIdx.x * blockDim.x + threadIdx.x; i < n; i += gridDim.x * blockDim.x)
    dst[i] = __float2bfloat16(src[i]);
}

// ---------------- tiled fp32 GEMM: C[m][n] = sum_k A[row(m)][k]*Bk[k][n] (+bias[n])
__global__ __launch_bounds__(256) void gemm32_kernel(const float* __restrict__ A,
                                                     const int* __restrict__ Xtb,
                                                     const float* __restrict__ Bk,
                                                     const float* __restrict__ bias,
                                                     float* __restrict__ C,
                                                     int N, int K, int ldb) {
  __shared__ float Xs[32][65];    // [k][m]
  __shared__ float Ws[32][129];   // [k][n]
  __shared__ int toks[64];
  int m0 = blockIdx.x * 64, n0 = blockIdx.y * 128;
  int tid = threadIdx.x;
  if (tid < 64) {
    int m = m0 + tid;
    toks[tid] = Xtb ? Xtb[(m & 63) * TT + (m >> 6)] : m;
  }
  __syncthreads();
  float acc[4][8];
#pragma unroll
  for (int i = 0; i < 4; ++i)
#pragma unroll
    for (int j = 0; j < 8; ++j) acc[i][j] = 0.f;
  int mi = (tid >> 4) * 4;   // 4 m per thread
  int ni = (tid & 15) * 8;   // 8 n per thread
  for (int kc = 0; kc < K; kc += 32) {
#pragma unroll
    for (int i = 0; i < 16; ++i) {
      int idx = tid + i * 256;          // 0..4095
      int kk = idx >> 7, nn = idx & 127;
      Ws[kk][nn] = Bk[(size_t)(kc + kk) * ldb + n0 + nn];
    }
#pragma unroll
    for (int i = 0; i < 8; ++i) {
      int idx = tid + i * 256;          // 0..2047
      int mm = idx >> 5, kk = idx & 31;
      Xs[kk][mm] = A[(size_t)toks[mm] * K + kc + kk];
    }
    __syncthreads();
#pragma unroll
    for (int k = 0; k < 32; ++k) {
      float xv[4], wv[8];
#pragma unroll
      for (int i = 0; i < 4; ++i) xv[i] = Xs[k][mi + i];
#pragma unroll
      for (int j = 0; j < 8; ++j) wv[j] = Ws[k][ni + j];
#pragma unroll
      for (int i = 0; i < 4; ++i)
#pragma unroll
        for (int j = 0; j < 8; ++j) acc[i][j] += xv[i] * wv[j];
    }
    __syncthreads();
  }
#pragma unroll
  for (int i = 0; i < 4; ++i) {
    int m = m0 + mi + i;
#pragma unroll
    for (int j = 0; j < 8; ++j) {
      int n = n0 + ni + j;
      C[(size_t)m * N + n] = acc[i][j] + (bias ? bias[n] : 0.f);
    }
  }
}

// ---------------- persistent recurrent kernel (256 blocks x 512 threads)
// Block blk owns output cols j0=2*blk, j0+1. Weights LDS-resident. State in
// natural [b][k] layout. 4 hand-rolled barriers per step.
struct RecArgs {
  const float *Wq, *W_ih0, *W_hh0, *W_ih1, *W_hh1;
  const float *b_hh0, *b_ih1, *b_hh1;
  const float *gix, *keysp, *enc, *wv;
  const int* vlen;
  float *q, *ctx, *h0a, *h0b, *h1a, *h1b;
  int* bar;
  __hip_bfloat16* outsb;
};

// one GRU layer: waves 0-3 accumulate Wi*x, waves 4-7 accumulate Wh*h.
template <int LAYER>
__device__ __forceinline__ void gru_phase(const RecArgs& a, const float (*WL)[1024],
                                          const float* __restrict__ X,
                                          const float* __restrict__ Hc,
                                          float* __restrict__ Hn,
                                          const float* __restrict__ biasI,
                                          const float* __restrict__ bhh, int t,
                                          int j0, int w, int lane, int tid,
                                          float (*red)[8][64]) {
  const float* xbase = (w < 4) ? X : Hc;
  const int kb = (w & 3) * 128;
  const float* xrow = xbase + (size_t)lane * HH + kb;
  const int wk = (w < 4) ? kb : 512 + kb;
  float s0 = 0, s1 = 0, s2 = 0, s3 = 0, s4 = 0, s5 = 0;
#pragma unroll 8
  for (int k = 0; k < 128; k += 4) {
    float4 x = *(const float4*)&xrow[k];
    float4 w0 = *(const float4*)&WL[0][wk + k];
    float4 w1 = *(const float4*)&WL[1][wk + k];
    float4 w2 = *(const float4*)&WL[2][wk + k];
    float4 w3 = *(const float4*)&WL[3][wk + k];
    float4 w4 = *(const float4*)&WL[4][wk + k];
    float4 w5 = *(const float4*)&WL[5][wk + k];
    s0 += w0.x * x.x + w0.y * x.y + w0.z * x.z + w0.w * x.w;
    s1 += w1.x * x.x + w1.y * x.y + w1.z * x.z + w1.w * x.w;
    s2 += w2.x * x.x + w2.y * x.y + w2.z * x.z + w2.w * x.w;
    s3 += w3.x * x.x + w3.y * x.y + w3.z * x.z + w3.w * x.w;
    s4 += w4.x * x.x + w4.y * x.y + w4.z * x.z + w4.w * x.w;
    s5 += w5.x * x.x + w5.y * x.y + w5.z * x.z + w5.w * x.w;
  }
  red[0][w][lane] = s0; red[1][w][lane] = s1;
  red[2][w][lane] = s2; red[3][w][lane] = s3;
  red[4][w][lane] = s4; red[5][w][lane] = s5;
  __syncthreads();
  if (tid < 128) {
    int b = tid & 63, jj = tid >> 6, j = j0 + jj;
    float Ri = 0, Rh = 0, Zi = 0, Zh = 0, Ni = 0, Nh = 0;
#pragma unroll
    for (int q = 0; q < 4; ++q) {
      Ri += red[jj][q][b];     Rh += red[jj][4 + q][b];
      Zi += red[2 + jj][q][b]; Zh += red[2 + jj][4 + q][b];
      Ni += red[4 + jj][q][b]; Nh += red[4 + jj][4 + q][b];
    }
    float gr, gz, gn;
    if (LAYER == 0) {
      const float* gx = biasI + (size_t)b * G3;
      gr = gx[j]; gz = gx[j + 512]; gn = gx[j + 1024];
    } else {
      gr = biasI[j]; gz = biasI[j + 512]; gn = biasI[j + 1024];
    }
    float r = sigmoid_fast(gr + Ri + bhh[j] + Rh);
    float z = sigmoid_fast(gz + Zi + bhh[j + 512] + Zh);
    float n = tanh_fast(gn + Ni + r * (bhh[j + 1024] + Nh));
    float hv = (1.f - z) * n + z * Hc[(size_t)b * HH + j];
    Hn[(size_t)b * HH + j] = hv;
    if (LAYER == 1) a.outsb[((size_t)t * BB + b) * HH + j] = __float2bfloat16(hv);
  }
}

__global__ __launch_bounds__(512) void recurrent_kernel(RecArgs a) {
  const int blk = blockIdx.x, tid = threadIdx.x;
  const int w = tid >> 6, lane = tid & 63;
  const int j0 = 2 * blk;

  __shared__ __align__(16) float WL0[6][1024];   // slots: r0,r1,z0,z1,n0,n1; k<512 Wi, k>=512 Wh
  __shared__ __align__(16) float WL1[6][1024];
  __shared__ __align__(16) float QL[2][512];
  __shared__ float red[6][8][64];
  __shared__ float sQ[512], sWV[512], sAttn[64];

  // one-time weight preload (rows of original matrices are contiguous)
  for (int idx = tid; idx < 6 * 1024; idx += 512) {
    int s = idx >> 10, k = idx & 1023;
    int g = s >> 1, jj = s & 1;
    int r = g * 512 + j0 + jj;
    WL0[s][k] = (k < 512) ? a.W_ih0[(size_t)r * 768 + k] : a.W_hh0[(size_t)r * 512 + (k - 512)];
    WL1[s][k] = (k < 512) ? a.W_ih1[(size_t)r * 512 + k] : a.W_hh1[(size_t)r * 512 + (k - 512)];
  }
  for (int idx = tid; idx < 1024; idx += 512) {
    int jj = idx >> 9, k = idx & 511;
    QL[jj][k] = a.Wq[(size_t)(j0 + jj) * HH + k];
  }
  sWV[tid] = a.wv[tid];
  const int vl = (blk < BB) ? a.vlen[blk] : 0;
  __syncthreads();

  float* h0buf[2] = {a.h0a, a.h0b};
  float* h1buf[2] = {a.h1a, a.h1b};

  for (int t = 0; t < TT; ++t) {
    const float* h0cur = h0buf[t & 1];
    float* h0nxt = h0buf[(t + 1) & 1];
    const float* h1cur = h1buf[t & 1];
    float* h1nxt = h1buf[(t + 1) & 1];

    // ---- P0: q[b][j0..j0+1] = h1cur[b][:] . Wq[j,:]  (j-distributed) ----
    {
      const float* xrow = h1cur + (size_t)lane * HH + w * 64;
      float q0 = 0, q1 = 0;
#pragma unroll 8
      for (int k = 0; k < 64; k += 4) {
        float4 x = *(const float4*)&xrow[k];
        float4 w0 = *(const float4*)&QL[0][w * 64 + k];
        float4 w1 = *(const float4*)&QL[1][w * 64 + k];
        q0 += w0.x * x.x + w0.y * x.y + w0.z * x.z + w0.w * x.w;
        q1 += w1.x * x.x + w1.y * x.y + w1.z * x.z + w1.w * x.w;
      }
      red[0][w][lane] = q0; red[1][w][lane] = q1;
      __syncthreads();
      if (tid < 128) {
        int b = tid & 63, jj = tid >> 6;
        float q = 0;
#pragma unroll
        for (int qq = 0; qq < 8; ++qq) q += red[jj][qq][b];
        a.q[(size_t)b * HH + j0 + jj] = q;
      }
    }
    gbar(a.bar, t * 4 + 0);

    // ---- P1: scores + softmax + context (blocks 0..63, b = blk) ----
    if (blk < BB) {
      const int b = blk;
      sQ[tid] = a.q[(size_t)b * HH + tid];
      __syncthreads();
      for (int s = w; s < SS; s += 8) {
        const float* kp = a.keysp + ((size_t)b * SS + s) * HH;
        float p = 0.f;
#pragma unroll
        for (int h = lane; h < HH; h += 64)
          p += tanh_fast(sQ[h] + kp[h]) * sWV[h];
#pragma unroll
        for (int off = 32; off > 0; off >>= 1) p += __shfl_down(p, off);
        if (lane == 0) sAttn[s] = (s < vl) ? p : -1e6f;
      }
      __syncthreads();
      if (w == 0) {
        float v = sAttn[lane];
        float mx = v;
        for (int off = 32; off > 0; off >>= 1) mx = fmaxf(mx, __shfl_xor(mx, off));
        float e = __expf(v - mx);
        float sm = e;
        for (int off = 32; off > 0; off >>= 1) sm += __shfl_xor(sm, off);
        sAttn[lane] = e / sm;
      }
      __syncthreads();
      float c = 0.f;
#pragma unroll 8
      for (int s = 0; s < SS; ++s) c += sAttn[s] * a.enc[((size_t)b * SS + s) * HH + tid];
      a.ctx[(size_t)b * HH + tid] = c;
    }
    gbar(a.bar, t * 4 + 1);

    // ---- P2: GRU layer 0 -> h0nxt ----
    gru_phase<0>(a, WL0, a.ctx, h0cur, h0nxt,
                 a.gix + (size_t)t * BB * G3, a.b_hh0, t, j0, w, lane, tid, red);
    gbar(a.bar, t * 4 + 2);

    // ---- P3: GRU layer 1 -> h1nxt (+ bf16 outs) ----
    gru_phase<1>(a, WL1, h0nxt, h1cur, h1nxt,
                 a.b_ih1, a.b_hh1, t, j0, w, lane, tid, red);
    gbar(a.bar, t * 4 + 3);
  }
}

// ---------------- final dense: C[m,v] = A[m,:] . Bt[v,:] + bias[v], scatter to [B,T,V]
__global__ __launch_bounds__(256) void dense_kernel(const __hip_bfloat16* __restrict__ A,
                                                    const __hip_bfloat16* __restrict__ Bt,
                                                    const float* __restrict__ bias,
                                                    float* __restrict__ out) {
  __shared__ __align__(16) short As[128 * 64];
  __shared__ __align__(16) short Bs[128 * 64];
  int mt = blockIdx.x;         // 0..31
  int nt = blockIdx.y;         // 0..249
  int tid = threadIdx.x;
  int w = tid >> 6, lane = tid & 63;
  int wm = w >> 1, wn = w & 1;
  f32x4 acc[4][4];
#pragma unroll
  for (int m = 0; m < 4; ++m)
#pragma unroll
    for (int n = 0; n < 4; ++n) acc[m][n] = (f32x4)0.f;

  const short* Ag = (const short*)A + (size_t)(mt * 128) * 512;
  const short* Bg = (const short*)Bt + (size_t)(nt * 128) * 512;

  for (int kt = 0; kt < 8; ++kt) {
    int k0 = kt * 64;
#pragma unroll
    for (int c = 0; c < 4; ++c) {
      int chunk = w * 4 + c;                  // 0..15, wave-uniform
      int row = chunk * 8 + (lane >> 3);      // 0..127
      int col = (lane & 7) * 8;               // bf16 col within 64
      async16(As + chunk * 512, Ag + (size_t)row * 512 + k0 + col);
      async16(Bs + chunk * 512, Bg + (size_t)row * 512 + k0 + col);
    }
    __syncthreads();
#pragma unroll
    for (int kk = 0; kk < 2; ++kk) {
      int krow = kk * 32 + (lane >> 4) * 8;
      bf16x8 af[4], bf[4];
#pragma unroll
      for (int m = 0; m < 4; ++m) {
        int r = wm * 64 + m * 16 + (lane & 15);
        af[m] = *(const bf16x8*)&As[r * 64 + krow];
      }
#pragma unroll
      for (int n = 0; n < 4; ++n) {
        int r = wn * 64 + n * 16 + (lane & 15);
        bf[n] = *(const bf16x8*)&Bs[r * 64 + krow];
      }
#pragma unroll
      for (int m = 0; m < 4; ++m)
#pragma unroll
        for (int n = 0; n < 4; ++n)
          acc[m][n] = __builtin_amdgcn_mfma_f32_16x16x32_bf16(af[m], bf[n], acc[m][n], 0, 0, 0);
    }
    __syncthreads();
  }
#pragma unroll
  for (int m = 0; m < 4; ++m) {
    int rbase = mt * 128 + wm * 64 + m * 16 + (lane >> 4) * 4;
#pragma unroll
    for (int n = 0; n < 4; ++n) {
      int v = nt * 128 + wn * 64 + n * 16 + (lane & 15);
      float bv = bias[v];
#pragma unroll
      for (int r = 0; r < 4; ++r) {
        int mi = rbase + r;                  // mi = t*64 + b
        size_t off = (size_t)(mi & 63) * (TT * VV) + (size_t)(mi >> 6) * VV + v;
        out[off] = acc[m][n][r] + bv;
      }
    }
  }
}

extern "C" void kernel_launch(void* const* d_in, const int* in_sizes, int n_in,
                              void* d_out, int out_size, void* d_ws, size_t ws_size,
                              hipStream_t stream) {
  const int*   X     = (const int*)d_in[0];
  const float* enc   = (const float*)d_in[1];
  const float* hs    = (const float*)d_in[2];
  const int*   vlen  = (const int*)d_in[3];
  const float* emb   = (const float*)d_in[4];
  const float* Wq    = (const float*)d_in[5];
  const float* Wk    = (const float*)d_in[6];
  const float* wv    = (const float*)d_in[7];
  const float* W_ih0 = (const float*)d_in[8];
  const float* W_hh0 = (const float*)d_in[9];
  const float* b_ih0 = (const float*)d_in[10];
  const float* b_hh0 = (const float*)d_in[11];
  const float* W_ih1 = (const float*)d_in[12];
  const float* W_hh1 = (const float*)d_in[13];
  const float* b_ih1 = (const float*)d_in[14];
  const float* b_hh1 = (const float*)d_in[15];
  const float* dW    = (const float*)d_in[16];
  const float* db    = (const float*)d_in[17];
  float* out = (float*)d_out;

  char* wp = (char*)d_ws;
  auto alloc = [&](size_t bytes) { char* p = wp; wp += (bytes + 255) & ~(size_t)255; return p; };
  __hip_bfloat16* dWb   = (__hip_bfloat16*)alloc((size_t)VV * HH * 2);
  __hip_bfloat16* outsb = (__hip_bfloat16*)alloc((size_t)TT * BB * HH * 2);
  float* keysp = (float*)alloc((size_t)BB * SS * HH * 4);
  float* gix   = (float*)alloc((size_t)TT * BB * G3 * 4);
  float* WkT   = (float*)alloc((size_t)HH * HH * 4);
  float* WT0e  = (float*)alloc((size_t)EE * G3 * 4);
  float* qbuf  = (float*)alloc((size_t)BB * HH * 4);
  float* ctx   = (float*)alloc((size_t)BB * HH * 4);
  float* h0a   = (float*)alloc((size_t)BB * HH * 4);
  float* h0b   = (float*)alloc((size_t)BB * HH * 4);
  float* h1a   = (float*)alloc((size_t)BB * HH * 4);
  float* h1b   = (float*)alloc((size_t)BB * HH * 4);
  int*   bar   = (int*)alloc(TT * 4 * sizeof(int));

  hipMemsetAsync(bar, 0, TT * 4 * sizeof(int), stream);

  dim3 tb(32, 8);
  // WkT[h][n] = Wk[n][h]
  transpose_kernel<<<dim3(HH / 32, HH / 32), tb, 0, stream>>>(WkT, Wk, HH, HH, HH, 0);
  // WT0e[e][n] = W_ih0[n][512+e]  (emb part of W_ih0, ld=768)
  transpose_kernel<<<dim3(EE / 32, G3 / 32), tb, 0, stream>>>(WT0e, W_ih0, G3, EE, HH + EE, HH);
  cast_kernel<<<2048, 256, 0, stream>>>(dW, dWb, VV * HH);

  // h state init: hs is [L][B][H] row-major = natural [b][k]
  hipMemcpyAsync(h0a, hs, (size_t)BB * HH * 4, hipMemcpyDeviceToDevice, stream);
  hipMemcpyAsync(h1a, hs + (size_t)BB * HH, (size_t)BB * HH * 4, hipMemcpyDeviceToDevice, stream);

  // keysp[b*S+s][n] = enc row . WkT   (M=4096,N=512,K=512)
  gemm32_kernel<<<dim3(BB * SS / 64, HH / 128), 256, 0, stream>>>(
      enc, nullptr, WkT, nullptr, keysp, HH, HH, HH);
  // gix[t*B+b][n] = emb[X[b,t]] . WT0e + b_ih0   (M=4096,N=1536,K=256)
  gemm32_kernel<<<dim3(TT * BB / 64, G3 / 128), 256, 0, stream>>>(
      emb, X, WT0e, b_ih0, gix, G3, EE, G3);

  RecArgs args;
  args.Wq = Wq; args.W_ih0 = W_ih0; args.W_hh0 = W_hh0; args.W_ih1 = W_ih1; args.W_hh1 = W_hh1;
  args.b_hh0 = b_hh0; args.b_ih1 = b_ih1; args.b_hh1 = b_hh1;
  args.gix = gix; args.keysp = keysp; args.enc = enc; args.wv = wv; args.vlen = vlen;
  args.q = qbuf; args.ctx = ctx;
  args.h0a = h0a; args.h0b = h0b; args.h1a = h1a; args.h1b = h1b;
  args.bar = bar; args.outsb = outsb;
  void* kp[] = {&args};
  hipLaunchCooperativeKernel(reinterpret_cast<void*>(recurrent_kernel),
                             dim3(NBLK), dim3(512), kp, 0, stream);

  dense_kernel<<<dim3(32, 250), 256, 0, stream>>>(outsb, dWb, db, out);
}

// Round 5
// 5841.460 us; speedup vs baseline: 2.0892x; 1.3135x over previous
//
#include <hip/hip_runtime.h>
#include <hip/hip_bf16.h>

#define VV 32000
#define EE 256
#define HH 512
#define BB 64
#define TT 64
#define SS 64
#define G3 1536   // 3*H
#define NBLK 256
#define STSZ (HH * BB)   // one state buffer, floats

typedef __attribute__((ext_vector_type(8))) short bf16x8;
typedef __attribute__((ext_vector_type(4))) float f32x4;

__device__ __forceinline__ void async16(void* lds, const void* g) {
  __builtin_amdgcn_global_load_lds((const __attribute__((address_space(1))) void*)g,
                                   (__attribute__((address_space(3))) void*)lds, 16, 0, 0);
}

__device__ __forceinline__ float sigmoid_fast(float x) {
  return 1.0f / (1.0f + __expf(-x));
}
__device__ __forceinline__ float tanh_fast(float x) {
  x = fminf(fmaxf(x, -15.f), 15.f);
  float e = __expf(2.f * x);
  return (e - 1.f) / (e + 1.f);
}

// coherent store: write-through past L2 to the IF coherence point (no fence needed)
__device__ __forceinline__ void stg_sc(float* p, float v) {
  asm volatile("global_store_dword %0, %1, off sc0 sc1" :: "v"(p), "v"(v) : "memory");
}

// fence-free one-shot grid barrier: syncthreads drains each wave's vmcnt (sc stores
// acked at coherence point), then a single relaxed agent atomic per block.
__device__ __forceinline__ void gbar(int* bar, int idx) {
  __syncthreads();
  if (threadIdx.x == 0) {
    __hip_atomic_fetch_add(&bar[idx], 1, __ATOMIC_RELAXED, __HIP_MEMORY_SCOPE_AGENT);
    while (__hip_atomic_load(&bar[idx], __ATOMIC_RELAXED, __HIP_MEMORY_SCOPE_AGENT) < NBLK) {}
  }
  __syncthreads();
}

// ---------------- strided 2D transpose: dst[c][r] = src[r*ld + off + c]
__global__ __launch_bounds__(256) void transpose_kernel(float* __restrict__ dst,
                                                        const float* __restrict__ src,
                                                        int R, int C, int ld, int off) {
  __shared__ float tile[32][33];
  int c0 = blockIdx.x * 32, r0 = blockIdx.y * 32;
  int x = threadIdx.x, y = threadIdx.y;     // block (32,8)
  for (int i = y; i < 32; i += 8) tile[i][x] = src[(size_t)(r0 + i) * ld + off + c0 + x];
  __syncthreads();
  for (int i = y; i < 32; i += 8) dst[(size_t)(c0 + i) * R + r0 + x] = tile[x][i];
}

// ---------------- fp32 -> bf16 cast
__global__ __launch_bounds__(256) void cast_kernel(const float* __restrict__ src,
                                                   __hip_bfloat16* __restrict__ dst, int n) {
  for (int i = blockIdx.x * blockDim.x + threadIdx.x; i < n; i += gridDim.x * blockDim.x)
    dst[i] = __float2bfloat16(src[i]);
}

// ---------------- transpose initial hidden state into [h][b] layout
__global__ __launch_bounds__(256) void hsT_kernel(const float* __restrict__ hs,
                                                  float* __restrict__ h0T,
                                                  float* __restrict__ h1T) {
  int i = blockIdx.x * 256 + threadIdx.x;   // 0..32767
  int b = i >> 9, h = i & 511;
  h0T[h * BB + b] = hs[b * HH + h];
  h1T[h * BB + b] = hs[BB * HH + b * HH + h];
}

// ---------------- tiled fp32 GEMM: C[m][n] = sum_k A[row(m)][k]*Bk[k][n] (+bias[n])
__global__ __launch_bounds__(256) void gemm32_kernel(const float* __restrict__ A,
                                                     const int* __restrict__ Xtb,
                                                     const float* __restrict__ Bk,
                                                     const float* __restrict__ bias,
                                                     float* __restrict__ C,
                                                     int N, int K, int ldb) {
  __shared__ float Xs[32][65];    // [k][m]
  __shared__ float Ws[32][129];   // [k][n]
  __shared__ int toks[64];
  int m0 = blockIdx.x * 64, n0 = blockIdx.y * 128;
  int tid = threadIdx.x;
  if (tid < 64) {
    int m = m0 + tid;
    toks[tid] = Xtb ? Xtb[(m & 63) * TT + (m >> 6)] : m;
  }
  __syncthreads();
  float acc[4][8];
#pragma unroll
  for (int i = 0; i < 4; ++i)
#pragma unroll
    for (int j = 0; j < 8; ++j) acc[i][j] = 0.f;
  int mi = (tid >> 4) * 4;   // 4 m per thread
  int ni = (tid & 15) * 8;   // 8 n per thread
  for (int kc = 0; kc < K; kc += 32) {
#pragma unroll
    for (int i = 0; i < 16; ++i) {
      int idx = tid + i * 256;          // 0..4095
      int kk = idx >> 7, nn = idx & 127;
      Ws[kk][nn] = Bk[(size_t)(kc + kk) * ldb + n0 + nn];
    }
#pragma unroll
    for (int i = 0; i < 8; ++i) {
      int idx = tid + i * 256;          // 0..2047
      int mm = idx >> 5, kk = idx & 31;
      Xs[kk][mm] = A[(size_t)toks[mm] * K + kc + kk];
    }
    __syncthreads();
#pragma unroll
    for (int k = 0; k < 32; ++k) {
      float xv[4], wv[8];
#pragma unroll
      for (int i = 0; i < 4; ++i) xv[i] = Xs[k][mi + i];
#pragma unroll
      for (int j = 0; j < 8; ++j) wv[j] = Ws[k][ni + j];
#pragma unroll
      for (int i = 0; i < 4; ++i)
#pragma unroll
        for (int j = 0; j < 8; ++j) acc[i][j] += xv[i] * wv[j];
    }
    __syncthreads();
  }
#pragma unroll
  for (int i = 0; i < 4; ++i) {
    int m = m0 + mi + i;
#pragma unroll
    for (int j = 0; j < 8; ++j) {
      int n = n0 + ni + j;
      C[(size_t)m * N + n] = acc[i][j] + (bias ? bias[n] : 0.f);
    }
  }
}

// ---------------- persistent recurrent kernel (256 blocks x 512 threads)
// Block blk owns output cols j0=2*blk, j0+1. Weights LDS-resident. State in
// [k][b] one-shot per-step buffers, sc0sc1 stores, plain cached reads.
// 3 fence-free barriers per step.
struct RecArgs {
  const float *WqT, *W_ih0, *W_hh0, *W_ih1, *W_hh1;
  const float *b_hh0, *b_ih1, *b_hh1;
  const float *gix, *keysp, *enc, *wv;
  const int* vlen;
  const float *h0init, *h1init;     // [k][b]
  float *ctxS, *h0S, *h1S;          // [TT][HH*BB] one-shot
  int* bar;
  __hip_bfloat16* outsb;
};

// one GRU layer: waves 0-3 accumulate Wi*x, waves 4-7 accumulate Wh*h (k-split).
template <int LAYER>
__device__ __forceinline__ void gru_phase(const RecArgs& a, const float (*WL)[1024],
                                          const float* __restrict__ X,
                                          const float* __restrict__ Hp,
                                          float* __restrict__ Hn,
                                          const float* __restrict__ biasI,
                                          const float* __restrict__ bhh, int t,
                                          int j0, int w, int lane, int tid,
                                          float (*red)[8][64]) {
  const float* xb = (w < 4) ? X : Hp;
  const int kb = (w & 3) * 128;
  const int wk = (w < 4) ? kb : 512 + kb;
  float s0 = 0, s1 = 0, s2 = 0, s3 = 0, s4 = 0, s5 = 0;
#pragma unroll 8
  for (int k = 0; k < 128; k += 4) {
    float x0 = xb[(kb + k) * BB + lane];
    float x1 = xb[(kb + k + 1) * BB + lane];
    float x2 = xb[(kb + k + 2) * BB + lane];
    float x3 = xb[(kb + k + 3) * BB + lane];
    float4 w0 = *(const float4*)&WL[0][wk + k];
    float4 w1 = *(const float4*)&WL[1][wk + k];
    float4 w2 = *(const float4*)&WL[2][wk + k];
    float4 w3 = *(const float4*)&WL[3][wk + k];
    float4 w4 = *(const float4*)&WL[4][wk + k];
    float4 w5 = *(const float4*)&WL[5][wk + k];
    s0 += w0.x * x0 + w0.y * x1 + w0.z * x2 + w0.w * x3;
    s1 += w1.x * x0 + w1.y * x1 + w1.z * x2 + w1.w * x3;
    s2 += w2.x * x0 + w2.y * x1 + w2.z * x2 + w2.w * x3;
    s3 += w3.x * x0 + w3.y * x1 + w3.z * x2 + w3.w * x3;
    s4 += w4.x * x0 + w4.y * x1 + w4.z * x2 + w4.w * x3;
    s5 += w5.x * x0 + w5.y * x1 + w5.z * x2 + w5.w * x3;
  }
  red[0][w][lane] = s0; red[1][w][lane] = s1;
  red[2][w][lane] = s2; red[3][w][lane] = s3;
  red[4][w][lane] = s4; red[5][w][lane] = s5;
  __syncthreads();
  if (tid < 128) {
    int b = tid & 63, jj = tid >> 6, j = j0 + jj;
    float Ri = 0, Rh = 0, Zi = 0, Zh = 0, Ni = 0, Nh = 0;
#pragma unroll
    for (int q = 0; q < 4; ++q) {
      Ri += red[jj][q][b];     Rh += red[jj][4 + q][b];
      Zi += red[2 + jj][q][b]; Zh += red[2 + jj][4 + q][b];
      Ni += red[4 + jj][q][b]; Nh += red[4 + jj][4 + q][b];
    }
    float gr, gz, gn;
    if (LAYER == 0) {
      const float* gx = biasI + (size_t)b * G3;
      gr = gx[j]; gz = gx[j + 512]; gn = gx[j + 1024];
    } else {
      gr = biasI[j]; gz = biasI[j + 512]; gn = biasI[j + 1024];
    }
    float r = sigmoid_fast(gr + Ri + bhh[j] + Rh);
    float z = sigmoid_fast(gz + Zi + bhh[j + 512] + Zh);
    float n = tanh_fast(gn + Ni + r * (bhh[j + 1024] + Nh));
    float hold = Hp[j * BB + b];
    float hv = (1.f - z) * n + z * hold;
    stg_sc(&Hn[j * BB + b], hv);
    if (LAYER == 1) a.outsb[((size_t)t * BB + b) * HH + j] = __float2bfloat16(hv);
  }
}

__global__ __launch_bounds__(512) void recurrent_kernel(RecArgs a) {
  const int blk = blockIdx.x, tid = threadIdx.x;
  const int w = tid >> 6, lane = tid & 63;
  const int j0 = 2 * blk;

  __shared__ __align__(16) float WL0[6][1024];   // slots r0,r1,z0,z1,n0,n1; k<512 Wi, k>=512 Wh
  __shared__ __align__(16) float WL1[6][1024];
  __shared__ float red[6][8][64];
  __shared__ float sH[HH], sQ[HH], sWV[HH], sAttn[SS];

  // one-time weight preload (rows of original matrices are contiguous)
  for (int idx = tid; idx < 6 * 1024; idx += 512) {
    int s = idx >> 10, k = idx & 1023;
    int g = s >> 1, jj = s & 1;
    int r = g * 512 + j0 + jj;
    WL0[s][k] = (k < 512) ? a.W_ih0[(size_t)r * 768 + k] : a.W_hh0[(size_t)r * 512 + (k - 512)];
    WL1[s][k] = (k < 512) ? a.W_ih1[(size_t)r * 512 + k] : a.W_hh1[(size_t)r * 512 + (k - 512)];
  }
  sWV[tid] = a.wv[tid];
  const int vl = (blk < BB) ? a.vlen[blk] : 0;
  __syncthreads();

  for (int t = 0; t < TT; ++t) {
    const float* h0p = (t == 0) ? a.h0init : a.h0S + (size_t)(t - 1) * STSZ;
    const float* h1p = (t == 0) ? a.h1init : a.h1S + (size_t)(t - 1) * STSZ;
    float* ctxt = a.ctxS + (size_t)t * STSZ;
    float* h0n  = a.h0S + (size_t)t * STSZ;
    float* h1n  = a.h1S + (size_t)t * STSZ;

    // ---- PA: q-proj + scores + softmax + context (blocks 0..63, b = blk) ----
    if (blk < BB) {
      const int b = blk;
      sH[tid] = h1p[(size_t)tid * BB + b];   // tid = k
      __syncthreads();
      float qv = 0.f;                        // q[tid] = dot(h1[b,:], WqT[:,tid])
#pragma unroll 8
      for (int k = 0; k < HH; ++k)
        qv += sH[k] * a.WqT[(size_t)k * HH + tid];
      sQ[tid] = qv;
      __syncthreads();
      for (int s = w; s < SS; s += 8) {
        const float* kp = a.keysp + ((size_t)b * SS + s) * HH;
        float p = 0.f;
#pragma unroll
        for (int h = lane; h < HH; h += 64)
          p += tanh_fast(sQ[h] + kp[h]) * sWV[h];
#pragma unroll
        for (int off = 32; off > 0; off >>= 1) p += __shfl_down(p, off);
        if (lane == 0) sAttn[s] = (s < vl) ? p : -1e6f;
      }
      __syncthreads();
      if (w == 0) {
        float v = sAttn[lane];
        float mx = v;
        for (int off = 32; off > 0; off >>= 1) mx = fmaxf(mx, __shfl_xor(mx, off));
        float e = __expf(v - mx);
        float sm = e;
        for (int off = 32; off > 0; off >>= 1) sm += __shfl_xor(sm, off);
        sAttn[lane] = e / sm;
      }
      __syncthreads();
      float c = 0.f;
#pragma unroll 8
      for (int s = 0; s < SS; ++s) c += sAttn[s] * a.enc[((size_t)b * SS + s) * HH + tid];
      stg_sc(&ctxt[(size_t)tid * BB + b], c);
    }
    gbar(a.bar, t * 3 + 0);

    // ---- PB: GRU layer 0 -> h0n ----
    gru_phase<0>(a, WL0, ctxt, h0p, h0n,
                 a.gix + (size_t)t * BB * G3, a.b_hh0, t, j0, w, lane, tid, red);
    gbar(a.bar, t * 3 + 1);

    // ---- PC: GRU layer 1 -> h1n (+ bf16 outs) ----
    gru_phase<1>(a, WL1, h0n, h1p, h1n,
                 a.b_ih1, a.b_hh1, t, j0, w, lane, tid, red);
    gbar(a.bar, t * 3 + 2);
  }
}

// ---------------- final dense: C[m,v] = A[m,:] . Bt[v,:] + bias[v], scatter to [B,T,V]
__global__ __launch_bounds__(256) void dense_kernel(const __hip_bfloat16* __restrict__ A,
                                                    const __hip_bfloat16* __restrict__ Bt,
                                                    const float* __restrict__ bias,
                                                    float* __restrict__ out) {
  __shared__ __align__(16) short As[128 * 64];
  __shared__ __align__(16) short Bs[128 * 64];
  int mt = blockIdx.x;         // 0..31
  int nt = blockIdx.y;         // 0..249
  int tid = threadIdx.x;
  int w = tid >> 6, lane = tid & 63;
  int wm = w >> 1, wn = w & 1;
  f32x4 acc[4][4];
#pragma unroll
  for (int m = 0; m < 4; ++m)
#pragma unroll
    for (int n = 0; n < 4; ++n) acc[m][n] = (f32x4)0.f;

  const short* Ag = (const short*)A + (size_t)(mt * 128) * 512;
  const short* Bg = (const short*)Bt + (size_t)(nt * 128) * 512;

  for (int kt = 0; kt < 8; ++kt) {
    int k0 = kt * 64;
#pragma unroll
    for (int c = 0; c < 4; ++c) {
      int chunk = w * 4 + c;                  // 0..15, wave-uniform
      int row = chunk * 8 + (lane >> 3);      // 0..127
      int col = (lane & 7) * 8;               // bf16 col within 64
      async16(As + chunk * 512, Ag + (size_t)row * 512 + k0 + col);
      async16(Bs + chunk * 512, Bg + (size_t)row * 512 + k0 + col);
    }
    __syncthreads();
#pragma unroll
    for (int kk = 0; kk < 2; ++kk) {
      int krow = kk * 32 + (lane >> 4) * 8;
      bf16x8 af[4], bf[4];
#pragma unroll
      for (int m = 0; m < 4; ++m) {
        int r = wm * 64 + m * 16 + (lane & 15);
        af[m] = *(const bf16x8*)&As[r * 64 + krow];
      }
#pragma unroll
      for (int n = 0; n < 4; ++n) {
        int r = wn * 64 + n * 16 + (lane & 15);
        bf[n] = *(const bf16x8*)&Bs[r * 64 + krow];
      }
#pragma unroll
      for (int m = 0; m < 4; ++m)
#pragma unroll
        for (int n = 0; n < 4; ++n)
          acc[m][n] = __builtin_amdgcn_mfma_f32_16x16x32_bf16(af[m], bf[n], acc[m][n], 0, 0, 0);
    }
    __syncthreads();
  }
#pragma unroll
  for (int m = 0; m < 4; ++m) {
    int rbase = mt * 128 + wm * 64 + m * 16 + (lane >> 4) * 4;
#pragma unroll
    for (int n = 0; n < 4; ++n) {
      int v = nt * 128 + wn * 64 + n * 16 + (lane & 15);
      float bv = bias[v];
#pragma unroll
      for (int r = 0; r < 4; ++r) {
        int mi = rbase + r;                  // mi = t*64 + b
        size_t off = (size_t)(mi & 63) * (TT * VV) + (size_t)(mi >> 6) * VV + v;
        out[off] = acc[m][n][r] + bv;
      }
    }
  }
}

extern "C" void kernel_launch(void* const* d_in, const int* in_sizes, int n_in,
                              void* d_out, int out_size, void* d_ws, size_t ws_size,
                              hipStream_t stream) {
  const int*   X     = (const int*)d_in[0];
  const float* enc   = (const float*)d_in[1];
  const float* hs    = (const float*)d_in[2];
  const int*   vlen  = (const int*)d_in[3];
  const float* emb   = (const float*)d_in[4];
  const float* Wq    = (const float*)d_in[5];
  const float* Wk    = (const float*)d_in[6];
  const float* wv    = (const float*)d_in[7];
  const float* W_ih0 = (const float*)d_in[8];
  const float* W_hh0 = (const float*)d_in[9];
  const float* b_ih0 = (const float*)d_in[10];
  const float* b_hh0 = (const float*)d_in[11];
  const float* W_ih1 = (const float*)d_in[12];
  const float* W_hh1 = (const float*)d_in[13];
  const float* b_ih1 = (const float*)d_in[14];
  const float* b_hh1 = (const float*)d_in[15];
  const float* dW    = (const float*)d_in[16];
  const float* db    = (const float*)d_in[17];
  float* out = (float*)d_out;

  char* wp = (char*)d_ws;
  auto alloc = [&](size_t bytes) { char* p = wp; wp += (bytes + 255) & ~(size_t)255; return p; };
  __hip_bfloat16* dWb   = (__hip_bfloat16*)alloc((size_t)VV * HH * 2);
  __hip_bfloat16* outsb = (__hip_bfloat16*)alloc((size_t)TT * BB * HH * 2);
  float* keysp = (float*)alloc((size_t)BB * SS * HH * 4);
  float* gix   = (float*)alloc((size_t)TT * BB * G3 * 4);
  float* WkT   = (float*)alloc((size_t)HH * HH * 4);
  float* WqT   = (float*)alloc((size_t)HH * HH * 4);
  float* WT0e  = (float*)alloc((size_t)EE * G3 * 4);
  float* h0T   = (float*)alloc((size_t)HH * BB * 4);
  float* h1T   = (float*)alloc((size_t)HH * BB * 4);
  float* ctxS  = (float*)alloc((size_t)TT * STSZ * 4);
  float* h0S   = (float*)alloc((size_t)TT * STSZ * 4);
  float* h1S   = (float*)alloc((size_t)TT * STSZ * 4);
  int*   bar   = (int*)alloc(TT * 3 * sizeof(int));

  hipMemsetAsync(bar, 0, TT * 3 * sizeof(int), stream);

  dim3 tb(32, 8);
  // WkT[h][n] = Wk[n][h];  WqT[h][j] = Wq[j][h]
  transpose_kernel<<<dim3(HH / 32, HH / 32), tb, 0, stream>>>(WkT, Wk, HH, HH, HH, 0);
  transpose_kernel<<<dim3(HH / 32, HH / 32), tb, 0, stream>>>(WqT, Wq, HH, HH, HH, 0);
  // WT0e[e][n] = W_ih0[n][512+e]  (emb part of W_ih0, ld=768)
  transpose_kernel<<<dim3(EE / 32, G3 / 32), tb, 0, stream>>>(WT0e, W_ih0, G3, EE, HH + EE, HH);
  cast_kernel<<<2048, 256, 0, stream>>>(dW, dWb, VV * HH);
  hsT_kernel<<<128, 256, 0, stream>>>(hs, h0T, h1T);

  // keysp[b*S+s][n] = enc row . WkT   (M=4096,N=512,K=512)
  gemm32_kernel<<<dim3(BB * SS / 64, HH / 128), 256, 0, stream>>>(
      enc, nullptr, WkT, nullptr, keysp, HH, HH, HH);
  // gix[t*B+b][n] = emb[X[b,t]] . WT0e + b_ih0   (M=4096,N=1536,K=256)
  gemm32_kernel<<<dim3(TT * BB / 64, G3 / 128), 256, 0, stream>>>(
      emb, X, WT0e, b_ih0, gix, G3, EE, G3);

  RecArgs args;
  args.WqT = WqT; args.W_ih0 = W_ih0; args.W_hh0 = W_hh0; args.W_ih1 = W_ih1; args.W_hh1 = W_hh1;
  args.b_hh0 = b_hh0; args.b_ih1 = b_ih1; args.b_hh1 = b_hh1;
  args.gix = gix; args.keysp = keysp; args.enc = enc; args.wv = wv; args.vlen = vlen;
  args.h0init = h0T; args.h1init = h1T;
  args.ctxS = ctxS; args.h0S = h0S; args.h1S = h1S;
  args.bar = bar; args.outsb = outsb;
  void* kp[] = {&args};
  hipLaunchCooperativeKernel(reinterpret_cast<void*>(recurrent_kernel),
                             dim3(NBLK), dim3(512), kp, 0, stream);

  dense_kernel<<<dim3(32, 250), 256, 0, stream>>>(outsb, dWb, db, out);
}

// Round 6
// 4292.912 us; speedup vs baseline: 2.8429x; 1.3607x over previous
//
#include <hip/hip_runtime.h>
#include <hip/hip_bf16.h>

#define VV 32000
#define EE 256
#define HH 512
#define BB 64
#define TT 64
#define SS 64
#define G3 1536   // 3*H
#define NBLK 256
#define STSZ (HH * BB)   // one state buffer, floats

typedef __attribute__((ext_vector_type(8))) short bf16x8;
typedef __attribute__((ext_vector_type(4))) float f32x4;

__device__ __forceinline__ void async16(void* lds, const void* g) {
  __builtin_amdgcn_global_load_lds((const __attribute__((address_space(1))) void*)g,
                                   (__attribute__((address_space(3))) void*)lds, 16, 0, 0);
}

__device__ __forceinline__ float sigmoid_fast(float x) {
  return 1.0f / (1.0f + __expf(-x));
}
__device__ __forceinline__ float tanh_fast(float x) {
  x = fminf(fmaxf(x, -15.f), 15.f);
  float e = __expf(2.f * x);
  return (e - 1.f) / (e + 1.f);
}

// coherent store: write-through past L2 to the IF coherence point (no fence needed)
__device__ __forceinline__ void stg_sc(float* p, float v) {
  asm volatile("global_store_dword %0, %1, off sc0 sc1" :: "v"(p), "v"(v) : "memory");
}

// fence-free one-shot grid barrier: syncthreads drains each wave's vmcnt (sc stores
// acked at coherence point), then a single relaxed agent atomic per block.
__device__ __forceinline__ void gbar(int* bar, int idx) {
  __syncthreads();
  if (threadIdx.x == 0) {
    __hip_atomic_fetch_add(&bar[idx], 1, __ATOMIC_RELAXED, __HIP_MEMORY_SCOPE_AGENT);
    while (__hip_atomic_load(&bar[idx], __ATOMIC_RELAXED, __HIP_MEMORY_SCOPE_AGENT) < NBLK)
      __builtin_amdgcn_s_sleep(1);
  }
  __syncthreads();
}

// ---------------- strided 2D transpose: dst[c][r] = src[r*ld + off + c]
__global__ __launch_bounds__(256) void transpose_kernel(float* __restrict__ dst,
                                                        const float* __restrict__ src,
                                                        int R, int C, int ld, int off) {
  __shared__ float tile[32][33];
  int c0 = blockIdx.x * 32, r0 = blockIdx.y * 32;
  int x = threadIdx.x, y = threadIdx.y;     // block (32,8)
  for (int i = y; i < 32; i += 8) tile[i][x] = src[(size_t)(r0 + i) * ld + off + c0 + x];
  __syncthreads();
  for (int i = y; i < 32; i += 8) dst[(size_t)(c0 + i) * R + r0 + x] = tile[x][i];
}

// ---------------- fp32 -> bf16 cast
__global__ __launch_bounds__(256) void cast_kernel(const float* __restrict__ src,
                                                   __hip_bfloat16* __restrict__ dst, int n) {
  for (int i = blockIdx.x * blockDim.x + threadIdx.x; i < n; i += gridDim.x * blockDim.x)
    dst[i] = __float2bfloat16(src[i]);
}

// ---------------- transpose initial hidden state into [h][b] layout
__global__ __launch_bounds__(256) void hsT_kernel(const float* __restrict__ hs,
                                                  float* __restrict__ h0T,
                                                  float* __restrict__ h1T) {
  int i = blockIdx.x * 256 + threadIdx.x;   // 0..32767
  int b = i >> 9, h = i & 511;
  h0T[h * BB + b] = hs[b * HH + h];
  h1T[h * BB + b] = hs[BB * HH + b * HH + h];
}

// ---------------- tiled fp32 GEMM: C = A(row-gathered) * Bk (+bias)
// tbmaj==0: C[m][n];  tbmaj==1: C[(m>>6)][n][m&63]  (i.e. [t][n][b] for m=t*64+b)
__global__ __launch_bounds__(256) void gemm32_kernel(const float* __restrict__ A,
                                                     const int* __restrict__ Xtb,
                                                     const float* __restrict__ Bk,
                                                     const float* __restrict__ bias,
                                                     float* __restrict__ C,
                                                     int N, int K, int ldb, int tbmaj) {
  __shared__ float Xs[32][65];    // [k][m]
  __shared__ float Ws[32][129];   // [k][n]
  __shared__ int toks[64];
  int m0 = blockIdx.x * 64, n0 = blockIdx.y * 128;
  int tid = threadIdx.x;
  if (tid < 64) {
    int m = m0 + tid;
    toks[tid] = Xtb ? Xtb[(m & 63) * TT + (m >> 6)] : m;
  }
  __syncthreads();
  float acc[4][8];
#pragma unroll
  for (int i = 0; i < 4; ++i)
#pragma unroll
    for (int j = 0; j < 8; ++j) acc[i][j] = 0.f;
  int mi = (tid >> 4) * 4;   // 4 m per thread
  int ni = (tid & 15) * 8;   // 8 n per thread
  for (int kc = 0; kc < K; kc += 32) {
#pragma unroll
    for (int i = 0; i < 16; ++i) {
      int idx = tid + i * 256;          // 0..4095
      int kk = idx >> 7, nn = idx & 127;
      Ws[kk][nn] = Bk[(size_t)(kc + kk) * ldb + n0 + nn];
    }
#pragma unroll
    for (int i = 0; i < 8; ++i) {
      int idx = tid + i * 256;          // 0..2047
      int mm = idx >> 5, kk = idx & 31;
      Xs[kk][mm] = A[(size_t)toks[mm] * K + kc + kk];
    }
    __syncthreads();
#pragma unroll
    for (int k = 0; k < 32; ++k) {
      float xv[4], wv[8];
#pragma unroll
      for (int i = 0; i < 4; ++i) xv[i] = Xs[k][mi + i];
#pragma unroll
      for (int j = 0; j < 8; ++j) wv[j] = Ws[k][ni + j];
#pragma unroll
      for (int i = 0; i < 4; ++i)
#pragma unroll
        for (int j = 0; j < 8; ++j) acc[i][j] += xv[i] * wv[j];
    }
    __syncthreads();
  }
#pragma unroll
  for (int i = 0; i < 4; ++i) {
    int m = m0 + mi + i;
#pragma unroll
    for (int j = 0; j < 8; ++j) {
      int n = n0 + ni + j;
      float v = acc[i][j] + (bias ? bias[n] : 0.f);
      if (tbmaj) C[((size_t)(m >> 6) * N + n) * BB + (m & 63)] = v;
      else       C[(size_t)m * N + n] = v;
    }
  }
}

// ---------------- persistent recurrent kernel (256 blocks x 512 threads)
// Block blk owns output cols j0=2*blk, j0+1 (q, h0, h1). Wq/GRU weight slices
// LDS-resident. State in [k][b] one-shot per-step buffers, sc0sc1 stores, plain
// cached reads. keysp/enc/gixT stay L2-resident (no 1MB/block WqT reads).
// 4 fence-free barriers per step.
struct RecArgs {
  const float *Wq, *W_ih0, *W_hh0, *W_ih1, *W_hh1;
  const float *b_hh0, *b_ih1, *b_hh1;
  const float *gixT, *keysp, *enc, *wv;   // gixT: [t][j(1536)][b]
  const int* vlen;
  const float *h0init, *h1init;     // [k][b]
  float *qS;                        // [TT][b][j]  one-shot
  float *ctxS, *h0S, *h1S;          // [TT][k][b]  one-shot
  int* bar;
  __hip_bfloat16* outsb;
};

// one GRU layer: waves 0-3 accumulate Wi*x, waves 4-7 accumulate Wh*h (k-split).
template <int LAYER>
__device__ __forceinline__ void gru_phase(const RecArgs& a, const float (*WL)[1024],
                                          const float* __restrict__ X,
                                          const float* __restrict__ Hp,
                                          float* __restrict__ Hn,
                                          const float* __restrict__ biasI,  // L0: gixT slice, L1: b_ih1
                                          const float* __restrict__ bhh, int t,
                                          int j0, int w, int lane, int tid,
                                          float (*red)[8][64]) {
  const float* xb = (w < 4) ? X : Hp;
  const int kb = (w & 3) * 128;
  const int wk = (w < 4) ? kb : 512 + kb;
  float s0 = 0, s1 = 0, s2 = 0, s3 = 0, s4 = 0, s5 = 0;
#pragma unroll 8
  for (int k = 0; k < 128; k += 4) {
    float x0 = xb[(kb + k) * BB + lane];
    float x1 = xb[(kb + k + 1) * BB + lane];
    float x2 = xb[(kb + k + 2) * BB + lane];
    float x3 = xb[(kb + k + 3) * BB + lane];
    float4 w0 = *(const float4*)&WL[0][wk + k];
    float4 w1 = *(const float4*)&WL[1][wk + k];
    float4 w2 = *(const float4*)&WL[2][wk + k];
    float4 w3 = *(const float4*)&WL[3][wk + k];
    float4 w4 = *(const float4*)&WL[4][wk + k];
    float4 w5 = *(const float4*)&WL[5][wk + k];
    s0 += w0.x * x0 + w0.y * x1 + w0.z * x2 + w0.w * x3;
    s1 += w1.x * x0 + w1.y * x1 + w1.z * x2 + w1.w * x3;
    s2 += w2.x * x0 + w2.y * x1 + w2.z * x2 + w2.w * x3;
    s3 += w3.x * x0 + w3.y * x1 + w3.z * x2 + w3.w * x3;
    s4 += w4.x * x0 + w4.y * x1 + w4.z * x2 + w4.w * x3;
    s5 += w5.x * x0 + w5.y * x1 + w5.z * x2 + w5.w * x3;
  }
  red[0][w][lane] = s0; red[1][w][lane] = s1;
  red[2][w][lane] = s2; red[3][w][lane] = s3;
  red[4][w][lane] = s4; red[5][w][lane] = s5;
  __syncthreads();
  if (tid < 128) {
    int b = tid & 63, jj = tid >> 6, j = j0 + jj;
    float Ri = 0, Rh = 0, Zi = 0, Zh = 0, Ni = 0, Nh = 0;
#pragma unroll
    for (int q = 0; q < 4; ++q) {
      Ri += red[jj][q][b];     Rh += red[jj][4 + q][b];
      Zi += red[2 + jj][q][b]; Zh += red[2 + jj][4 + q][b];
      Ni += red[4 + jj][q][b]; Nh += red[4 + jj][4 + q][b];
    }
    float gr, gz, gn;
    if (LAYER == 0) {
      gr = biasI[(size_t)j * BB + b];
      gz = biasI[(size_t)(j + 512) * BB + b];
      gn = biasI[(size_t)(j + 1024) * BB + b];
    } else {
      gr = biasI[j]; gz = biasI[j + 512]; gn = biasI[j + 1024];
    }
    float r = sigmoid_fast(gr + Ri + bhh[j] + Rh);
    float z = sigmoid_fast(gz + Zi + bhh[j + 512] + Zh);
    float n = tanh_fast(gn + Ni + r * (bhh[j + 1024] + Nh));
    float hold = Hp[j * BB + b];
    float hv = (1.f - z) * n + z * hold;
    stg_sc(&Hn[j * BB + b], hv);
    if (LAYER == 1) a.outsb[((size_t)t * BB + b) * HH + j] = __float2bfloat16(hv);
  }
}

__global__ __launch_bounds__(512) void recurrent_kernel(RecArgs a) {
  const int blk = blockIdx.x, tid = threadIdx.x;
  const int w = tid >> 6, lane = tid & 63;
  const int j0 = 2 * blk;

  __shared__ __align__(16) float WL0[6][1024];   // slots r0,r1,z0,z1,n0,n1; k<512 Wi, k>=512 Wh
  __shared__ __align__(16) float WL1[6][1024];
  __shared__ __align__(16) float QL[2][512];     // Wq rows j0, j0+1
  __shared__ float red[6][8][64];
  __shared__ float sQ[HH], sWV[HH], sAttn[SS];

  // one-time weight preload (rows of original matrices are contiguous)
  for (int idx = tid; idx < 6 * 1024; idx += 512) {
    int s = idx >> 10, k = idx & 1023;
    int g = s >> 1, jj = s & 1;
    int r = g * 512 + j0 + jj;
    WL0[s][k] = (k < 512) ? a.W_ih0[(size_t)r * 768 + k] : a.W_hh0[(size_t)r * 512 + (k - 512)];
    WL1[s][k] = (k < 512) ? a.W_ih1[(size_t)r * 512 + k] : a.W_hh1[(size_t)r * 512 + (k - 512)];
  }
  for (int idx = tid; idx < 1024; idx += 512) {
    int jj = idx >> 9, k = idx & 511;
    QL[jj][k] = a.Wq[(size_t)(j0 + jj) * HH + k];
  }
  sWV[tid] = a.wv[tid];
  const int vl = (blk < BB) ? a.vlen[blk] : 0;
  __syncthreads();

  for (int t = 0; t < TT; ++t) {
    const float* h0p = (t == 0) ? a.h0init : a.h0S + (size_t)(t - 1) * STSZ;
    const float* h1p = (t == 0) ? a.h1init : a.h1S + (size_t)(t - 1) * STSZ;
    float* qrowT = a.qS + (size_t)t * BB * HH;   // [b][j]
    float* ctxt = a.ctxS + (size_t)t * STSZ;
    float* h0n  = a.h0S + (size_t)t * STSZ;
    float* h1n  = a.h1S + (size_t)t * STSZ;

    // ---- P0: q[b][j0..j0+1] = h1p[b,:] . Wq[j,:]  (j-distributed, k-split 8 waves) ----
    {
      const float* xk = h1p + (size_t)(w * 64) * BB;
      float q0 = 0.f, q1 = 0.f;
#pragma unroll 8
      for (int k = 0; k < 64; ++k) {
        float x = xk[k * BB + lane];
        q0 += QL[0][w * 64 + k] * x;
        q1 += QL[1][w * 64 + k] * x;
      }
      red[0][w][lane] = q0; red[1][w][lane] = q1;
      __syncthreads();
      if (tid < 64) {
        int b = tid;
        float v0 = 0.f, v1 = 0.f;
#pragma unroll
        for (int q = 0; q < 8; ++q) { v0 += red[0][q][b]; v1 += red[1][q][b]; }
        stg_sc(&qrowT[(size_t)b * HH + j0], v0);
        stg_sc(&qrowT[(size_t)b * HH + j0 + 1], v1);
      }
    }
    gbar(a.bar, t * 4 + 0);

    // ---- P1: scores + softmax + context (blocks 0..63, b = blk) ----
    if (blk < BB) {
      const int b = blk;
      sQ[tid] = qrowT[(size_t)b * HH + tid];   // coalesced 2KB, one-shot
      __syncthreads();
      for (int s = w; s < SS; s += 8) {
        const float* kp = a.keysp + ((size_t)b * SS + s) * HH;
        float p = 0.f;
#pragma unroll
        for (int h = lane; h < HH; h += 64)
          p += tanh_fast(sQ[h] + kp[h]) * sWV[h];
#pragma unroll
        for (int off = 32; off > 0; off >>= 1) p += __shfl_down(p, off);
        if (lane == 0) sAttn[s] = (s < vl) ? p : -1e6f;
      }
      __syncthreads();
      if (w == 0) {
        float v = sAttn[lane];
        float mx = v;
        for (int off = 32; off > 0; off >>= 1) mx = fmaxf(mx, __shfl_xor(mx, off));
        float e = __expf(v - mx);
        float sm = e;
        for (int off = 32; off > 0; off >>= 1) sm += __shfl_xor(sm, off);
        sAttn[lane] = e / sm;
      }
      __syncthreads();
      float c = 0.f;
#pragma unroll 8
      for (int s = 0; s < SS; ++s) c += sAttn[s] * a.enc[((size_t)b * SS + s) * HH + tid];
      stg_sc(&ctxt[(size_t)tid * BB + b], c);
    }
    gbar(a.bar, t * 4 + 1);

    // ---- P2: GRU layer 0 -> h0n ----
    gru_phase<0>(a, WL0, ctxt, h0p, h0n,
                 a.gixT + (size_t)t * G3 * BB, a.b_hh0, t, j0, w, lane, tid, red);
    gbar(a.bar, t * 4 + 2);

    // ---- P3: GRU layer 1 -> h1n (+ bf16 outs) ----
    gru_phase<1>(a, WL1, h0n, h1p, h1n,
                 a.b_ih1, a.b_hh1, t, j0, w, lane, tid, red);
    gbar(a.bar, t * 4 + 3);
  }
}

// ---------------- final dense: C[m,v] = A[m,:] . Bt[v,:] + bias[v], scatter to [B,T,V]
__global__ __launch_bounds__(256) void dense_kernel(const __hip_bfloat16* __restrict__ A,
                                                    const __hip_bfloat16* __restrict__ Bt,
                                                    const float* __restrict__ bias,
                                                    float* __restrict__ out) {
  __shared__ __align__(16) short As[128 * 64];
  __shared__ __align__(16) short Bs[128 * 64];
  int mt = blockIdx.x;         // 0..31
  int nt = blockIdx.y;         // 0..249
  int tid = threadIdx.x;
  int w = tid >> 6, lane = tid & 63;
  int wm = w >> 1, wn = w & 1;
  f32x4 acc[4][4];
#pragma unroll
  for (int m = 0; m < 4; ++m)
#pragma unroll
    for (int n = 0; n < 4; ++n) acc[m][n] = (f32x4)0.f;

  const short* Ag = (const short*)A + (size_t)(mt * 128) * 512;
  const short* Bg = (const short*)Bt + (size_t)(nt * 128) * 512;

  for (int kt = 0; kt < 8; ++kt) {
    int k0 = kt * 64;
#pragma unroll
    for (int c = 0; c < 4; ++c) {
      int chunk = w * 4 + c;                  // 0..15, wave-uniform
      int row = chunk * 8 + (lane >> 3);      // 0..127
      int col = (lane & 7) * 8;               // bf16 col within 64
      async16(As + chunk * 512, Ag + (size_t)row * 512 + k0 + col);
      async16(Bs + chunk * 512, Bg + (size_t)row * 512 + k0 + col);
    }
    __syncthreads();
#pragma unroll
    for (int kk = 0; kk < 2; ++kk) {
      int krow = kk * 32 + (lane >> 4) * 8;
      bf16x8 af[4], bf[4];
#pragma unroll
      for (int m = 0; m < 4; ++m) {
        int r = wm * 64 + m * 16 + (lane & 15);
        af[m] = *(const bf16x8*)&As[r * 64 + krow];
      }
#pragma unroll
      for (int n = 0; n < 4; ++n) {
        int r = wn * 64 + n * 16 + (lane & 15);
        bf[n] = *(const bf16x8*)&Bs[r * 64 + krow];
      }
#pragma unroll
      for (int m = 0; m < 4; ++m)
#pragma unroll
        for (int n = 0; n < 4; ++n)
          acc[m][n] = __builtin_amdgcn_mfma_f32_16x16x32_bf16(af[m], bf[n], acc[m][n], 0, 0, 0);
    }
    __syncthreads();
  }
#pragma unroll
  for (int m = 0; m < 4; ++m) {
    int rbase = mt * 128 + wm * 64 + m * 16 + (lane >> 4) * 4;
#pragma unroll
    for (int n = 0; n < 4; ++n) {
      int v = nt * 128 + wn * 64 + n * 16 + (lane & 15);
      float bv = bias[v];
#pragma unroll
      for (int r = 0; r < 4; ++r) {
        int mi = rbase + r;                  // mi = t*64 + b
        size_t off = (size_t)(mi & 63) * (TT * VV) + (size_t)(mi >> 6) * VV + v;
        out[off] = acc[m][n][r] + bv;
      }
    }
  }
}

extern "C" void kernel_launch(void* const* d_in, const int* in_sizes, int n_in,
                              void* d_out, int out_size, void* d_ws, size_t ws_size,
                              hipStream_t stream) {
  const int*   X     = (const int*)d_in[0];
  const float* enc   = (const float*)d_in[1];
  const float* hs    = (const float*)d_in[2];
  const int*   vlen  = (const int*)d_in[3];
  const float* emb   = (const float*)d_in[4];
  const float* Wq    = (const float*)d_in[5];
  const float* Wk    = (const float*)d_in[6];
  const float* wv    = (const float*)d_in[7];
  const float* W_ih0 = (const float*)d_in[8];
  const float* W_hh0 = (const float*)d_in[9];
  const float* b_ih0 = (const float*)d_in[10];
  const float* b_hh0 = (const float*)d_in[11];
  const float* W_ih1 = (const float*)d_in[12];
  const float* W_hh1 = (const float*)d_in[13];
  const float* b_ih1 = (const float*)d_in[14];
  const float* b_hh1 = (const float*)d_in[15];
  const float* dW    = (const float*)d_in[16];
  const float* db    = (const float*)d_in[17];
  float* out = (float*)d_out;

  char* wp = (char*)d_ws;
  auto alloc = [&](size_t bytes) { char* p = wp; wp += (bytes + 255) & ~(size_t)255; return p; };
  __hip_bfloat16* dWb   = (__hip_bfloat16*)alloc((size_t)VV * HH * 2);
  __hip_bfloat16* outsb = (__hip_bfloat16*)alloc((size_t)TT * BB * HH * 2);
  float* keysp = (float*)alloc((size_t)BB * SS * HH * 4);
  float* gixT  = (float*)alloc((size_t)TT * G3 * BB * 4);
  float* WkT   = (float*)alloc((size_t)HH * HH * 4);
  float* WT0e  = (float*)alloc((size_t)EE * G3 * 4);
  float* h0T   = (float*)alloc((size_t)HH * BB * 4);
  float* h1T   = (float*)alloc((size_t)HH * BB * 4);
  float* qS    = (float*)alloc((size_t)TT * BB * HH * 4);
  float* ctxS  = (float*)alloc((size_t)TT * STSZ * 4);
  float* h0S   = (float*)alloc((size_t)TT * STSZ * 4);
  float* h1S   = (float*)alloc((size_t)TT * STSZ * 4);
  int*   bar   = (int*)alloc(TT * 4 * sizeof(int));

  hipMemsetAsync(bar, 0, TT * 4 * sizeof(int), stream);

  dim3 tb(32, 8);
  // WkT[h][n] = Wk[n][h]
  transpose_kernel<<<dim3(HH / 32, HH / 32), tb, 0, stream>>>(WkT, Wk, HH, HH, HH, 0);
  // WT0e[e][n] = W_ih0[n][512+e]  (emb part of W_ih0, ld=768)
  transpose_kernel<<<dim3(EE / 32, G3 / 32), tb, 0, stream>>>(WT0e, W_ih0, G3, EE, HH + EE, HH);
  cast_kernel<<<2048, 256, 0, stream>>>(dW, dWb, VV * HH);
  hsT_kernel<<<128, 256, 0, stream>>>(hs, h0T, h1T);

  // keysp[b*S+s][n] = enc row . WkT   (M=4096,N=512,K=512)
  gemm32_kernel<<<dim3(BB * SS / 64, HH / 128), 256, 0, stream>>>(
      enc, nullptr, WkT, nullptr, keysp, HH, HH, HH, 0);
  // gixT[t][n][b] = emb[X[b,t]] . WT0e + b_ih0   (M=4096,N=1536,K=256, tb-major out)
  gemm32_kernel<<<dim3(TT * BB / 64, G3 / 128), 256, 0, stream>>>(
      emb, X, WT0e, b_ih0, gixT, G3, EE, G3, 1);

  RecArgs args;
  args.Wq = Wq; args.W_ih0 = W_ih0; args.W_hh0 = W_hh0; args.W_ih1 = W_ih1; args.W_hh1 = W_hh1;
  args.b_hh0 = b_hh0; args.b_ih1 = b_ih1; args.b_hh1 = b_hh1;
  args.gixT = gixT; args.keysp = keysp; args.enc = enc; args.wv = wv; args.vlen = vlen;
  args.h0init = h0T; args.h1init = h1T;
  args.qS = qS; args.ctxS = ctxS; args.h0S = h0S; args.h1S = h1S;
  args.bar = bar; args.outsb = outsb;
  void* kp[] = {&args};
  hipLaunchCooperativeKernel(reinterpret_cast<void*>(recurrent_kernel),
                             dim3(NBLK), dim3(512), kp, 0, stream);

  dense_kernel<<<dim3(32, 250), 256, 0, stream>>>(outsb, dWb, db, out);
}